// Round 4
// baseline (6687.352 us; speedup 1.0000x reference)
//
#include <hip/hip_runtime.h>
#include <hip/hip_bf16.h>

// HGT forward, MI355X. Round 4: inputs fp32, OUTPUT fp32 (reference dtype!).
// Round-3 bug: wrote bf16 into the fp32 d_out. Now layer-1 blend gemms write
// fp32 directly into d_out. Q still parks as bf16 in d_out (consumed before
// the fp32 epilogue overwrites, in-order stream).
// Fusion: k_r = x @ (kw.a_rel) + (kb.a_rel) -> per-relation fused fp32 weights.
// Softmax without max-subtraction (logits are O(0.01); mathematically equal).
// ws usage ~214.5 MB, guarded (soft-fail zeros output if too small).

typedef __hip_bfloat16 bf16;

#define N_STMT 100000
#define N_FUNC 50000
#define N_TOT  150000
#define EDGES  200000
#define CCH 128

__device__ __forceinline__ float b2f(bf16 x){ return __bfloat162float(x); }

__device__ __forceinline__ float gelu_f(float x){
  // jax.nn.gelu approximate=True (tanh form)
  return 0.5f * x * (1.f + tanhf(0.7978845608028654f * (x + 0.044715f * x * x * x)));
}

// ---------------- embedding mean-pool + relu ---------------------------------
__global__ __launch_bounds__(128) void pool_embed(
    const int* __restrict__ tok_s, const int* __restrict__ tok_f,
    const float* __restrict__ emb, float* __restrict__ E_out)
{
  int n = blockIdx.x, c = threadIdx.x;
  const int* tok = (n < N_STMT) ? (tok_s + n * 16) : (tok_f + (n - N_STMT) * 16);
  float acc = 0.f;
#pragma unroll
  for (int t = 0; t < 16; t++) {
    int v = tok[t];
    acc += emb[(long)v * CCH + c];
  }
  acc *= (1.f / 16.f);
  E_out[(long)n * CCH + c] = fmaxf(acc, 0.f);
}

// ---------------- generic [N,128]@[128,128]+bias GEMM ------------------------
// A, W, bias fp32. OT: output dtype (float or bf16).
// GELU_IN: gelu on A at LDS load. RELU_OUT: relu on store.
// BLEND: r = g*r + (1-g)*oldx[row], g = sigmoid(*skip_p). Reads oldx, writes dst.
template <typename OT, bool GELU_IN, bool RELU_OUT, bool BLEND>
__global__ __launch_bounds__(256) void gemm128(
    const float* __restrict__ A, const float* __restrict__ W,
    const float* __restrict__ bias, const float* __restrict__ oldx,
    OT* __restrict__ dst, int N, const float* __restrict__ skip_p)
{
  __shared__ float sA[64][68];    // 64 rows x BK=64 (+4 pad)
  __shared__ float sW[64][128];   // BK=64 x 128 cols
  const int tid = threadIdx.x;
  const int tr = tid >> 5, tc = tid & 31;   // 8 row-groups x 32 col-groups
  const long tileRow = (long)blockIdx.x * 64;

  float acc[8][4];
#pragma unroll
  for (int i = 0; i < 8; i++)
#pragma unroll
    for (int j = 0; j < 4; j++) acc[i][j] = 0.f;

  for (int kk = 0; kk < 128; kk += 64) {
#pragma unroll
    for (int m = 0; m < 4; m++) {
      int lin = tid + m * 256;
      int row = lin >> 4, c4 = (lin & 15) << 2;
      long gr = tileRow + row;
      float4 v = make_float4(0.f, 0.f, 0.f, 0.f);
      if (gr < N) v = *(const float4*)(A + gr * CCH + kk + c4);
      if (GELU_IN) { v.x = gelu_f(v.x); v.y = gelu_f(v.y); v.z = gelu_f(v.z); v.w = gelu_f(v.w); }
      *(float4*)(&sA[row][c4]) = v;
    }
#pragma unroll
    for (int m = 0; m < 8; m++) {
      int lin = tid + m * 256;
      int k = lin >> 5, c4 = (lin & 31) << 2;
      *(float4*)(&sW[k][c4]) = *(const float4*)(W + (kk + k) * CCH + c4);
    }
    __syncthreads();
#pragma unroll
    for (int k4 = 0; k4 < 16; k4++) {
      float4 w0 = *(const float4*)(&sW[k4 * 4 + 0][tc * 4]);
      float4 w1 = *(const float4*)(&sW[k4 * 4 + 1][tc * 4]);
      float4 w2 = *(const float4*)(&sW[k4 * 4 + 2][tc * 4]);
      float4 w3 = *(const float4*)(&sW[k4 * 4 + 3][tc * 4]);
#pragma unroll
      for (int i = 0; i < 8; i++) {
        float4 a = *(const float4*)(&sA[tr * 8 + i][k4 * 4]);
        acc[i][0] += a.x * w0.x + a.y * w1.x + a.z * w2.x + a.w * w3.x;
        acc[i][1] += a.x * w0.y + a.y * w1.y + a.z * w2.y + a.w * w3.y;
        acc[i][2] += a.x * w0.z + a.y * w1.z + a.z * w2.z + a.w * w3.z;
        acc[i][3] += a.x * w0.w + a.y * w1.w + a.z * w2.w + a.w * w3.w;
      }
    }
    __syncthreads();
  }

  float g = 1.f, gi = 0.f;
  if (BLEND) {
    float sk = *skip_p;
    g = 1.f / (1.f + expf(-sk));
    gi = 1.f - g;
  }
  float4 bv = *(const float4*)(bias + tc * 4);
#pragma unroll
  for (int i = 0; i < 8; i++) {
    long gr = tileRow + tr * 8 + i;
    if (gr < N) {
      float4 r = make_float4(acc[i][0] + bv.x, acc[i][1] + bv.y,
                             acc[i][2] + bv.z, acc[i][3] + bv.w);
      if (RELU_OUT) { r.x = fmaxf(r.x, 0.f); r.y = fmaxf(r.y, 0.f);
                      r.z = fmaxf(r.z, 0.f); r.w = fmaxf(r.w, 0.f); }
      if (BLEND) {
        float4 o = *(const float4*)(oldx + gr * CCH + tc * 4);
        r.x = g * r.x + gi * o.x; r.y = g * r.y + gi * o.y;
        r.z = g * r.z + gi * o.z; r.w = g * r.w + gi * o.w;
      }
      if constexpr (__is_same(OT, float)) {
        *(float4*)(dst + gr * CCH + tc * 4) = r;
      } else {
        union { ushort4 u; bf16 h[4]; } o;
        o.h[0] = __float2bfloat16(r.x); o.h[1] = __float2bfloat16(r.y);
        o.h[2] = __float2bfloat16(r.z); o.h[3] = __float2bfloat16(r.w);
        *(ushort4*)(dst + gr * CCH + tc * 4) = o.u;
      }
    }
  }
}

// -------- fused relation weights: Wr[c][h*16+e] = sum_d W[c][h*16+d]*rel[h][d][e]
__global__ __launch_bounds__(256) void make_wr(
    const float* __restrict__ W, const float* __restrict__ b,
    const float* __restrict__ rel, float* __restrict__ Wr, float* __restrict__ br)
{
  int idx = blockIdx.x * 256 + threadIdx.x;
  if (idx < 128 * 128) {
    int c = idx >> 7, o = idx & 127;
    int h = o >> 4, e = o & 15;
    float acc = 0.f;
#pragma unroll
    for (int d = 0; d < 16; d++)
      acc += W[c * 128 + h * 16 + d] * rel[h * 256 + d * 16 + e];
    Wr[c * 128 + o] = acc;
  }
  if (idx < 128) {
    int h = idx >> 4, e = idx & 15;
    float acc = 0.f;
#pragma unroll
    for (int d = 0; d < 16; d++)
      acc += b[h * 16 + d] * rel[h * 256 + d * 16 + e];
    br[idx] = acc;
  }
}

// -------- per-edge exp(logit) + denominator accumulate (Q/KR bf16) ----------
__global__ __launch_bounds__(256) void attn_logits(
    const int* __restrict__ src, const int* __restrict__ dst,
    const bf16* __restrict__ Q, const bf16* __restrict__ KR,
    const float* __restrict__ p_rel, float* __restrict__ LOGB,
    float* __restrict__ S)
{
  int t = blockIdx.x * 256 + threadIdx.x;
  int e = t >> 3, h = t & 7;
  int s_ = src[e], d_ = dst[e];
  const float4* qp = (const float4*)(Q + (long)d_ * CCH + h * 16);
  const float4* kp = (const float4*)(KR + (long)s_ * CCH + h * 16);
  union { float4 f; bf16 h8[8]; } q0, q1, k0, k1;
  q0.f = qp[0]; q1.f = qp[1]; k0.f = kp[0]; k1.f = kp[1];
  float acc = 0.f;
#pragma unroll
  for (int i = 0; i < 8; i++) acc += b2f(q0.h8[i]) * b2f(k0.h8[i]);
#pragma unroll
  for (int i = 0; i < 8; i++) acc += b2f(q1.h8[i]) * b2f(k1.h8[i]);
  float lg = acc * 0.25f * p_rel[h];   // scale = 1/sqrt(16)
  float ev = expf(lg);
  LOGB[e * 8 + h] = ev;
  atomicAdd(&S[d_ * 8 + h], ev);
}

// -------- msg scatter: AGG[dst] += alpha * VR[src] (VR bf16) ----------------
__global__ __launch_bounds__(256) void attn_agg(
    const int* __restrict__ src, const int* __restrict__ dst,
    const bf16* __restrict__ VR, const float* __restrict__ LOGB,
    const float* __restrict__ S, float* __restrict__ AGG)
{
  int t = blockIdx.x * 256 + threadIdx.x;
  int e = t >> 4, q = t & 15;          // 16 lanes/edge, 8 channels each
  int c0 = q << 3, h = q >> 1;
  int s_ = src[e], d_ = dst[e];
  float alpha = LOGB[e * 8 + h] / (S[d_ * 8 + h] + 1e-16f);
  union { float4 f; bf16 h8[8]; } v;
  v.f = *(const float4*)(VR + (long)s_ * CCH + c0);
  float* ap = AGG + (long)d_ * CCH + c0;
#pragma unroll
  for (int j = 0; j < 8; j++) atomicAdd(ap + j, b2f(v.h8[j]) * alpha);
}

__global__ __launch_bounds__(256) void zero_out_k(float* __restrict__ out)
{
  long i = ((long)blockIdx.x * 256 + threadIdx.x) * 4;
  *(float4*)(out + i) = make_float4(0.f, 0.f, 0.f, 0.f);
}

extern "C" void kernel_launch(void* const* d_in, const int* in_sizes, int n_in,
                              void* d_out, int out_size, void* d_ws, size_t ws_size,
                              hipStream_t stream)
{
  const int* tok_s = (const int*)d_in[0];
  const int* tok_f = (const int*)d_in[1];
  const int* esrc[3] = {(const int*)d_in[2], (const int*)d_in[4], (const int*)d_in[6]};
  const int* edst[3] = {(const int*)d_in[3], (const int*)d_in[5], (const int*)d_in[7]};
  const float* emb   = (const float*)d_in[8];
  const float* lin_w = (const float*)d_in[9];
  const float* lin_b = (const float*)d_in[10];
  const float* kw = (const float*)d_in[11];
  const float* kb = (const float*)d_in[12];
  const float* qw = (const float*)d_in[13];
  const float* qb = (const float*)d_in[14];
  const float* vw = (const float*)d_in[15];
  const float* vb = (const float*)d_in[16];
  const float* aw = (const float*)d_in[17];
  const float* ab = (const float*)d_in[18];
  const float* skip  = (const float*)d_in[19];
  const float* a_rel = (const float*)d_in[20];
  const float* m_rel = (const float*)d_in[21];
  const float* p_rel = (const float*)d_in[22];

  // ws layout: fp32 block then bf16 block. Total ~214.5 MB.
  float* ws   = (float*)d_ws;
  float* X    = ws;                    // 19,200,000 f
  float* AGG  = X    + 19200000L;      // 19,200,000 f (also pooled-E temp)
  float* LOGB = AGG  + 19200000L;      //  1,600,000 f
  float* S    = LOGB + 1600000L;       //    800,000 f
  float* KWr  = S    + 800000L;        //     16,384 f
  float* KBr  = KWr + 16384;           //        128 f
  float* VWr  = KBr + 128;             //     16,384 f
  float* VBr  = VWr + 16384;           //        128 f
  bf16*  KRb  = (bf16*)(VBr + 128);    // 12,800,000 bf16
  bf16*  VRb  = KRb + 12800000L;       // 12,800,000 bf16
  bf16*  Qb   = (bf16*)d_out;          // bf16 scratch in fp32 d_out, consumed
                                       // before the fp32 epilogue overwrites
  float* OUTF = (float*)d_out;         // final fp32 output

  const size_t NEED = (size_t)(19200000L*2 + 1600000 + 800000 + 2*(16384+128)) * 4
                    + (size_t)12800000L * 2 * 2;
  if (ws_size < NEED) {            // soft-fail diagnostic: absmax == |ref|max
    zero_out_k<<<19200000 / 4 / 256, 256, 0, stream>>>(OUTF);
    return;
  }

  const int  Ntype[2] = {N_STMT, N_FUNC};
  const long off[2]   = {0L, (long)N_STMT * CCH};
  const int  est[3] = {0, 0, 1}, edt[3] = {0, 1, 0};

  // prologue: pooled embeddings -> per-type linear+relu -> X
  pool_embed<<<N_TOT, 128, 0, stream>>>(tok_s, tok_f, emb, AGG);
  for (int t = 0; t < 2; t++)
    gemm128<float, false, true, false><<<(Ntype[t] + 63) / 64, 256, 0, stream>>>(
        AGG + off[t], lin_w + t * 16384, lin_b + t * 128, nullptr,
        X + off[t], Ntype[t], nullptr);

  for (int l = 0; l < 2; l++) {
    for (int t = 0; t < 2; t++)      // Q projections -> bf16 scratch in d_out
      gemm128<bf16, false, false, false><<<(Ntype[t] + 63) / 64, 256, 0, stream>>>(
          X + off[t], qw + (l * 2 + t) * 16384, qb + (l * 2 + t) * 128, nullptr,
          Qb + off[t], Ntype[t], nullptr);
    hipMemsetAsync(AGG, 0, (size_t)19200000 * 4, stream);

    for (int r = 0; r < 3; r++) {
      int st = est[r], dt = edt[r];
      make_wr<<<64, 256, 0, stream>>>(kw + (l * 2 + st) * 16384, kb + (l * 2 + st) * 128,
                                      a_rel + (l * 3 + r) * 2048, KWr, KBr);
      make_wr<<<64, 256, 0, stream>>>(vw + (l * 2 + st) * 16384, vb + (l * 2 + st) * 128,
                                      m_rel + (l * 3 + r) * 2048, VWr, VBr);
      gemm128<bf16, false, false, false><<<(Ntype[st] + 63) / 64, 256, 0, stream>>>(
          X + off[st], KWr, KBr, nullptr, KRb, Ntype[st], nullptr);
      gemm128<bf16, false, false, false><<<(Ntype[st] + 63) / 64, 256, 0, stream>>>(
          X + off[st], VWr, VBr, nullptr, VRb, Ntype[st], nullptr);
      hipMemsetAsync(S, 0, (size_t)Ntype[dt] * 8 * 4, stream);
      attn_logits<<<EDGES * 8 / 256, 256, 0, stream>>>(
          esrc[r], edst[r], Qb + off[dt], KRb, p_rel + (l * 3 + r) * 8, LOGB, S);
      attn_agg<<<EDGES * 16 / 256, 256, 0, stream>>>(
          esrc[r], edst[r], VRb, LOGB, S, AGG + off[dt]);
    }
    // out-proj + gated skip blend. l=0: write X. l=1: write fp32 d_out.
    for (int t = 0; t < 2; t++) {
      float* dst = (l == 0) ? (X + off[t]) : (OUTF + off[t]);
      gemm128<float, true, false, true><<<(Ntype[t] + 63) / 64, 256, 0, stream>>>(
          AGG + off[t], aw + (l * 2 + t) * 16384, ab + (l * 2 + t) * 128,
          X + off[t], dst, Ntype[t], skip + l * 2 + t);
    }
  }
}

// Round 5
// 2834.664 us; speedup vs baseline: 2.3591x; 2.3591x over previous
//
#include <hip/hip_runtime.h>
#include <hip/hip_bf16.h>

// HGT forward, MI355X. Round 5: CSR-based atomic-free edge aggregation.
// R4 profile: attn_agg atomics caused 800MB HBM writes/dispatch (6x709us).
// Now: build CSR on-device once per launch; one wave per dst node computes
// softmax denominator + weighted V-sum in registers (shfl_xor per-head dots),
// single non-atomic store. attn_logits/LOGB/S/AGG-memset eliminated.
// Q kept fp32 in d_out (consumed before the fp32 epilogue overwrites it).
// ws usage ~210.1 MB (< proven 214.5), guarded.

typedef __hip_bfloat16 bf16;

#define N_STMT 100000
#define N_FUNC 50000
#define N_TOT  150000
#define EDGES  200000
#define CCH 128

__device__ __forceinline__ float b2f(bf16 x){ return __bfloat162float(x); }

__device__ __forceinline__ float gelu_f(float x){
  // jax.nn.gelu approximate=True (tanh form)
  return 0.5f * x * (1.f + tanhf(0.7978845608028654f * (x + 0.044715f * x * x * x)));
}

// ---------------- embedding mean-pool + relu ---------------------------------
__global__ __launch_bounds__(128) void pool_embed(
    const int* __restrict__ tok_s, const int* __restrict__ tok_f,
    const float* __restrict__ emb, float* __restrict__ E_out)
{
  int n = blockIdx.x, c = threadIdx.x;
  const int* tok = (n < N_STMT) ? (tok_s + n * 16) : (tok_f + (n - N_STMT) * 16);
  float acc = 0.f;
#pragma unroll
  for (int t = 0; t < 16; t++) {
    int v = tok[t];
    acc += emb[(long)v * CCH + c];
  }
  acc *= (1.f / 16.f);
  E_out[(long)n * CCH + c] = fmaxf(acc, 0.f);
}

// ---------------- generic [N,128]@[128,128]+bias GEMM ------------------------
template <typename OT, bool GELU_IN, bool RELU_OUT, bool BLEND>
__global__ __launch_bounds__(256) void gemm128(
    const float* __restrict__ A, const float* __restrict__ W,
    const float* __restrict__ bias, const float* __restrict__ oldx,
    OT* __restrict__ dst, int N, const float* __restrict__ skip_p)
{
  __shared__ float sA[64][68];    // 64 rows x BK=64 (+4 pad)
  __shared__ float sW[64][128];   // BK=64 x 128 cols
  const int tid = threadIdx.x;
  const int tr = tid >> 5, tc = tid & 31;
  const long tileRow = (long)blockIdx.x * 64;

  float acc[8][4];
#pragma unroll
  for (int i = 0; i < 8; i++)
#pragma unroll
    for (int j = 0; j < 4; j++) acc[i][j] = 0.f;

  for (int kk = 0; kk < 128; kk += 64) {
#pragma unroll
    for (int m = 0; m < 4; m++) {
      int lin = tid + m * 256;
      int row = lin >> 4, c4 = (lin & 15) << 2;
      long gr = tileRow + row;
      float4 v = make_float4(0.f, 0.f, 0.f, 0.f);
      if (gr < N) v = *(const float4*)(A + gr * CCH + kk + c4);
      if (GELU_IN) { v.x = gelu_f(v.x); v.y = gelu_f(v.y); v.z = gelu_f(v.z); v.w = gelu_f(v.w); }
      *(float4*)(&sA[row][c4]) = v;
    }
#pragma unroll
    for (int m = 0; m < 8; m++) {
      int lin = tid + m * 256;
      int k = lin >> 5, c4 = (lin & 31) << 2;
      *(float4*)(&sW[k][c4]) = *(const float4*)(W + (kk + k) * CCH + c4);
    }
    __syncthreads();
#pragma unroll
    for (int k4 = 0; k4 < 16; k4++) {
      float4 w0 = *(const float4*)(&sW[k4 * 4 + 0][tc * 4]);
      float4 w1 = *(const float4*)(&sW[k4 * 4 + 1][tc * 4]);
      float4 w2 = *(const float4*)(&sW[k4 * 4 + 2][tc * 4]);
      float4 w3 = *(const float4*)(&sW[k4 * 4 + 3][tc * 4]);
#pragma unroll
      for (int i = 0; i < 8; i++) {
        float4 a = *(const float4*)(&sA[tr * 8 + i][k4 * 4]);
        acc[i][0] += a.x * w0.x + a.y * w1.x + a.z * w2.x + a.w * w3.x;
        acc[i][1] += a.x * w0.y + a.y * w1.y + a.z * w2.y + a.w * w3.y;
        acc[i][2] += a.x * w0.z + a.y * w1.z + a.z * w2.z + a.w * w3.z;
        acc[i][3] += a.x * w0.w + a.y * w1.w + a.z * w2.w + a.w * w3.w;
      }
    }
    __syncthreads();
  }

  float g = 1.f, gi = 0.f;
  if (BLEND) {
    float sk = *skip_p;
    g = 1.f / (1.f + expf(-sk));
    gi = 1.f - g;
  }
  float4 bv = *(const float4*)(bias + tc * 4);
#pragma unroll
  for (int i = 0; i < 8; i++) {
    long gr = tileRow + tr * 8 + i;
    if (gr < N) {
      float4 r = make_float4(acc[i][0] + bv.x, acc[i][1] + bv.y,
                             acc[i][2] + bv.z, acc[i][3] + bv.w);
      if (RELU_OUT) { r.x = fmaxf(r.x, 0.f); r.y = fmaxf(r.y, 0.f);
                      r.z = fmaxf(r.z, 0.f); r.w = fmaxf(r.w, 0.f); }
      if (BLEND) {
        float4 o = *(const float4*)(oldx + gr * CCH + tc * 4);
        r.x = g * r.x + gi * o.x; r.y = g * r.y + gi * o.y;
        r.z = g * r.z + gi * o.z; r.w = g * r.w + gi * o.w;
      }
      if constexpr (__is_same(OT, float)) {
        *(float4*)(dst + gr * CCH + tc * 4) = r;
      } else {
        union { ushort4 u; bf16 h[4]; } o;
        o.h[0] = __float2bfloat16(r.x); o.h[1] = __float2bfloat16(r.y);
        o.h[2] = __float2bfloat16(r.z); o.h[3] = __float2bfloat16(r.w);
        *(ushort4*)(dst + gr * CCH + tc * 4) = o.u;
      }
    }
  }
}

// -------- fused relation weights: Wr[c][h*16+e] = sum_d W[c][h*16+d]*rel[h][d][e]
__global__ __launch_bounds__(256) void make_wr(
    const float* __restrict__ W, const float* __restrict__ b,
    const float* __restrict__ rel, float* __restrict__ Wr, float* __restrict__ br)
{
  int idx = blockIdx.x * 256 + threadIdx.x;
  if (idx < 128 * 128) {
    int c = idx >> 7, o = idx & 127;
    int h = o >> 4, e = o & 15;
    float acc = 0.f;
#pragma unroll
    for (int d = 0; d < 16; d++)
      acc += W[c * 128 + h * 16 + d] * rel[h * 256 + d * 16 + e];
    Wr[c * 128 + o] = acc;
  }
  if (idx < 128) {
    int h = idx >> 4, e = idx & 15;
    float acc = 0.f;
#pragma unroll
    for (int d = 0; d < 16; d++)
      acc += b[h * 16 + d] * rel[h * 256 + d * 16 + e];
    br[idx] = acc;
  }
}

// ---------------- CSR build --------------------------------------------------
__global__ __launch_bounds__(256) void csr_count(
    const int* __restrict__ dst, int* __restrict__ deg, int* __restrict__ pos)
{
  int e = blockIdx.x * 256 + threadIdx.x;
  if (e < EDGES) pos[e] = atomicAdd(&deg[dst[e]], 1);
}
__global__ __launch_bounds__(256) void csr_alloc(
    const int* __restrict__ deg, int* __restrict__ rowstart,
    int* __restrict__ total, int Ndst)
{
  int n = blockIdx.x * 256 + threadIdx.x;
  if (n < Ndst) rowstart[n] = atomicAdd(total, deg[n]);
}
__global__ __launch_bounds__(256) void csr_fill(
    const int* __restrict__ dst, const int* __restrict__ rowstart,
    const int* __restrict__ pos, int* __restrict__ eidx)
{
  int e = blockIdx.x * 256 + threadIdx.x;
  if (e < EDGES) eidx[rowstart[dst[e]] + pos[e]] = e;
}

// -------- fused per-node attention aggregation (one wave per dst node) ------
// lane l owns channels 2l,2l+1; head h = l>>3 (8 lanes per 16-ch head).
// ACCUM: AGG += result (relation r2 adds to r0's stmt aggregate).
template <bool ACCUM>
__global__ __launch_bounds__(256) void agg_rel(
    const int* __restrict__ rowstart, const int* __restrict__ deg,
    const int* __restrict__ eidx, const int* __restrict__ src,
    const float* __restrict__ Qf, const bf16* __restrict__ KR,
    const bf16* __restrict__ VR, const float* __restrict__ p_rel,
    float* __restrict__ AGG, int Ndst)
{
  int n = blockIdx.x * 4 + (threadIdx.x >> 6);
  if (n >= Ndst) return;
  int l = threadIdx.x & 63;
  int h = l >> 3;
  float p = p_rel[h] * 0.25f;          // includes 1/sqrt(D)
  float2 q = *(const float2*)(Qf + (long)n * CCH + 2 * l);
  int rs = rowstart[n], g = deg[n];
  float accx = 0.f, accy = 0.f, den = 0.f;
  for (int j = 0; j < g; j++) {
    int e = eidx[rs + j];
    int s = src[e];
    union { uint u; bf16 hh[2]; } kv, vv;
    kv.u = *(const uint*)(KR + (long)s * CCH + 2 * l);
    float prod = q.x * b2f(kv.hh[0]) + q.y * b2f(kv.hh[1]);
    prod += __shfl_xor(prod, 1);
    prod += __shfl_xor(prod, 2);
    prod += __shfl_xor(prod, 4);       // all 8 lanes of head h hold the dot
    float ev = expf(prod * p);
    den += ev;
    vv.u = *(const uint*)(VR + (long)s * CCH + 2 * l);
    accx += ev * b2f(vv.hh[0]);
    accy += ev * b2f(vv.hh[1]);
  }
  float inv = 1.f / (den + 1e-16f);
  accx *= inv; accy *= inv;
  float* ap = AGG + (long)n * CCH + 2 * l;
  if (ACCUM) {
    float2 old = *(const float2*)ap;
    accx += old.x; accy += old.y;
  }
  *(float2*)ap = make_float2(accx, accy);
}

__global__ __launch_bounds__(256) void zero_out_k(float* __restrict__ out)
{
  long i = ((long)blockIdx.x * 256 + threadIdx.x) * 4;
  *(float4*)(out + i) = make_float4(0.f, 0.f, 0.f, 0.f);
}

extern "C" void kernel_launch(void* const* d_in, const int* in_sizes, int n_in,
                              void* d_out, int out_size, void* d_ws, size_t ws_size,
                              hipStream_t stream)
{
  const int* tok_s = (const int*)d_in[0];
  const int* tok_f = (const int*)d_in[1];
  const int* esrc[3] = {(const int*)d_in[2], (const int*)d_in[4], (const int*)d_in[6]};
  const int* edst[3] = {(const int*)d_in[3], (const int*)d_in[5], (const int*)d_in[7]};
  const float* emb   = (const float*)d_in[8];
  const float* lin_w = (const float*)d_in[9];
  const float* lin_b = (const float*)d_in[10];
  const float* kw = (const float*)d_in[11];
  const float* kb = (const float*)d_in[12];
  const float* qw = (const float*)d_in[13];
  const float* qb = (const float*)d_in[14];
  const float* vw = (const float*)d_in[15];
  const float* vb = (const float*)d_in[16];
  const float* aw = (const float*)d_in[17];
  const float* ab = (const float*)d_in[18];
  const float* skip  = (const float*)d_in[19];
  const float* a_rel = (const float*)d_in[20];
  const float* m_rel = (const float*)d_in[21];
  const float* p_rel = (const float*)d_in[22];

  // ---- ws layout: fp32 | bf16 | int. Total 210,132,112 B. ----
  float* ws   = (float*)d_ws;
  float* X    = ws;                    // 19,200,000 f
  float* AGG  = X    + 19200000L;      // 19,200,000 f (also pooled-E temp)
  float* KWr  = AGG  + 19200000L;      //     16,384 f
  float* KBr  = KWr + 16384;           //        128 f
  float* VWr  = KBr + 128;             //     16,384 f
  float* VBr  = VWr + 16384;           //        128 f
  bf16*  KRb  = (bf16*)(VBr + 128);    // 12,800,000 bf16 (reused per relation)
  bf16*  VRb  = KRb + 12800000L;       // 12,800,000 bf16
  int*   ip   = (int*)(VRb + 12800000L);
  // zeroed region: deg0,deg1,deg2,total[4]  (250,004 ints)
  int* deg[3]      = {ip, ip + 100000, ip + 150000};
  int* total       = ip + 250000;                      // 4 counters (3 used)
  int* rowstart[3] = {ip + 250004, ip + 350004, ip + 400004};
  int* eidx[3]     = {ip + 500004, ip + 700004, ip + 900004};
  int* pos         = ip + 1100004;                     // 200,000 (shared)
  // end: ip + 1,300,004 ints

  float* Qf   = (float*)d_out;         // fp32 Q scratch in d_out, consumed
  float* OUTF = (float*)d_out;         // before the epilogue overwrites it

  const size_t NEED = (size_t)(19200000L * 2 + 2 * (16384 + 128)) * 4
                    + (size_t)12800000L * 2 * 2 + (size_t)1300004 * 4;
  if (ws_size < NEED) {            // soft-fail diagnostic: absmax == |ref|max
    zero_out_k<<<19200000 / 4 / 256, 256, 0, stream>>>(OUTF);
    return;
  }

  const int  Ntype[2] = {N_STMT, N_FUNC};
  const long off[2]   = {0L, (long)N_STMT * CCH};
  const int  est[3] = {0, 0, 1}, edt[3] = {0, 1, 0};
  const int  EB = (EDGES + 255) / 256;

  // ---- CSR build (per relation), reused by both layers ----
  hipMemsetAsync(ip, 0, (size_t)250004 * 4, stream);
  for (int r = 0; r < 3; r++) {
    int Nd = Ntype[edt[r]];
    csr_count<<<EB, 256, 0, stream>>>(edst[r], deg[r], pos);
    csr_alloc<<<(Nd + 255) / 256, 256, 0, stream>>>(deg[r], rowstart[r], total + r, Nd);
    csr_fill<<<EB, 256, 0, stream>>>(edst[r], rowstart[r], pos, eidx[r]);
  }

  // ---- prologue: pooled embeddings -> per-type linear+relu -> X ----
  pool_embed<<<N_TOT, 128, 0, stream>>>(tok_s, tok_f, emb, AGG);
  for (int t = 0; t < 2; t++)
    gemm128<float, false, true, false><<<(Ntype[t] + 63) / 64, 256, 0, stream>>>(
        AGG + off[t], lin_w + t * 16384, lin_b + t * 128, nullptr,
        X + off[t], Ntype[t], nullptr);

  for (int l = 0; l < 2; l++) {
    for (int t = 0; t < 2; t++)      // Q projections -> fp32 scratch in d_out
      gemm128<float, false, false, false><<<(Ntype[t] + 63) / 64, 256, 0, stream>>>(
          X + off[t], qw + (l * 2 + t) * 16384, qb + (l * 2 + t) * 128, nullptr,
          Qf + off[t], Ntype[t], nullptr);

    for (int r = 0; r < 3; r++) {
      int st = est[r], dt = edt[r];
      int Nd = Ntype[dt];
      make_wr<<<64, 256, 0, stream>>>(kw + (l * 2 + st) * 16384, kb + (l * 2 + st) * 128,
                                      a_rel + (l * 3 + r) * 2048, KWr, KBr);
      make_wr<<<64, 256, 0, stream>>>(vw + (l * 2 + st) * 16384, vb + (l * 2 + st) * 128,
                                      m_rel + (l * 3 + r) * 2048, VWr, VBr);
      gemm128<bf16, false, false, false><<<(Ntype[st] + 63) / 64, 256, 0, stream>>>(
          X + off[st], KWr, KBr, nullptr, KRb, Ntype[st], nullptr);
      gemm128<bf16, false, false, false><<<(Ntype[st] + 63) / 64, 256, 0, stream>>>(
          X + off[st], VWr, VBr, nullptr, VRb, Ntype[st], nullptr);
      if (r == 2)   // stmt-dst: accumulate onto r0's aggregate
        agg_rel<true><<<(Nd + 3) / 4, 256, 0, stream>>>(
            rowstart[r], deg[r], eidx[r], esrc[r], Qf + off[dt], KRb, VRb,
            p_rel + (l * 3 + r) * 8, AGG + off[dt], Nd);
      else
        agg_rel<false><<<(Nd + 3) / 4, 256, 0, stream>>>(
            rowstart[r], deg[r], eidx[r], esrc[r], Qf + off[dt], KRb, VRb,
            p_rel + (l * 3 + r) * 8, AGG + off[dt], Nd);
    }
    // out-proj + gated skip blend. l=0: write X. l=1: write fp32 d_out.
    for (int t = 0; t < 2; t++) {
      float* dstp = (l == 0) ? (X + off[t]) : (OUTF + off[t]);
      gemm128<float, true, false, true><<<(Ntype[t] + 63) / 64, 256, 0, stream>>>(
          AGG + off[t], aw + (l * 2 + t) * 16384, ab + (l * 2 + t) * 128,
          X + off[t], dstp, Ntype[t], skip + l * 2 + t);
    }
  }
}

// Round 6
// 1219.903 us; speedup vs baseline: 5.4819x; 2.3237x over previous
//
#include <hip/hip_runtime.h>
#include <hip/hip_bf16.h>

// HGT forward, MI355X. Round 6: MFMA bf16 GEMMs (LDS-free), CSR aggregation.
// R5 profile: fp32 VALU gemm128 = 196us/dispatch, 10% occupancy, MfmaUtil 0.
// Now: v_mfma_f32_16x16x32_bf16, one wave per 32 rows x 128 cols. A-frags
// straight from global (rows wave-exclusive, read once); B-frags from
// pre-transposed bf16 weights (32KB, L1/L2-hot). No LDS, no barriers.
// Residual X kept bf16; Q bf16 parked in d_out. ws ~172 MB, guarded.

typedef __hip_bfloat16 bf16;
typedef __attribute__((ext_vector_type(8))) short short8;
typedef __attribute__((ext_vector_type(4))) float floatx4;

#define N_STMT 100000
#define N_FUNC 50000
#define N_TOT  150000
#define EDGES  200000
#define CCH 128

__device__ __forceinline__ float b2f(bf16 x){ return __bfloat162float(x); }
__device__ __forceinline__ short f2bs(float x){
  union { bf16 h; short s; } u; u.h = __float2bfloat16(x); return u.s;
}
__device__ __forceinline__ float gelu_f(float x){
  // jax.nn.gelu approximate=True (tanh form)
  return 0.5f * x * (1.f + tanhf(0.7978845608028654f * (x + 0.044715f * x * x * x)));
}

// ---------------- embedding mean-pool + relu -> bf16 -------------------------
__global__ __launch_bounds__(128) void pool_embed(
    const int* __restrict__ tok_s, const int* __restrict__ tok_f,
    const float* __restrict__ emb, bf16* __restrict__ E_out)
{
  int n = blockIdx.x, c = threadIdx.x;
  const int* tok = (n < N_STMT) ? (tok_s + n * 16) : (tok_f + (n - N_STMT) * 16);
  float acc = 0.f;
#pragma unroll
  for (int t = 0; t < 16; t++) {
    int v = tok[t];
    acc += emb[(long)v * CCH + c];
  }
  acc *= (1.f / 16.f);
  E_out[(long)n * CCH + c] = __float2bfloat16(fmaxf(acc, 0.f));
}

// ---------------- transpose+cast 10 raw weight matrices ---------------------
// out[mat][n*128+k] = bf16(src[mat][k*128+n]); mats: lin_w(2), qw(4), aw(4)
__global__ __launch_bounds__(256) void transp_w(
    const float* __restrict__ lin_w, const float* __restrict__ qw,
    const float* __restrict__ aw, bf16* __restrict__ out)
{
  int mat = blockIdx.y;
  const float* src = (mat < 2) ? lin_w + mat * 16384
                   : (mat < 6) ? qw + (mat - 2) * 16384
                               : aw + (mat - 6) * 16384;
  bf16* dst = out + mat * 16384;
  int idx = blockIdx.x * 256 + threadIdx.x;       // n*128+k
  int n = idx >> 7, k = idx & 127;
  dst[idx] = __float2bfloat16(src[k * 128 + n]);
}

// -------- fused relation weights, TRANSPOSED bf16 out -----------------------
// Wrt[o][c] = sum_d W[c][h*16+d]*rel[h][d][e], o = h*16+e. Bias fp32.
__global__ __launch_bounds__(256) void make_wr(
    const float* __restrict__ W, const float* __restrict__ b,
    const float* __restrict__ rel, bf16* __restrict__ Wrt, float* __restrict__ br)
{
  int idx = blockIdx.x * 256 + threadIdx.x;
  if (idx < 128 * 128) {
    int c = idx >> 7, o = idx & 127;
    int h = o >> 4, e = o & 15;
    float acc = 0.f;
#pragma unroll
    for (int d = 0; d < 16; d++)
      acc += W[c * 128 + h * 16 + d] * rel[h * 256 + d * 16 + e];
    Wrt[o * 128 + c] = __float2bfloat16(acc);
  }
  if (idx < 128) {
    int h = idx >> 4, e = idx & 15;
    float acc = 0.f;
#pragma unroll
    for (int d = 0; d < 16; d++)
      acc += b[h * 16 + d] * rel[h * 256 + d * 16 + e];
    br[idx] = acc;
  }
}

// ---------------- MFMA GEMM: [N,128] @ [128,128] + bias ---------------------
// Wave w of 4 owns rows blockIdx.x*128 + w*32 .. +31, all 128 cols.
// A: bf16 rows (AGELU=false) or fp32 rows with gelu (AGELU=true).
// Wt: bf16 transposed weights Wt[n][k]. BLEND: v = g*v + (1-g)*oldx (bf16).
template <bool AGELU, bool RELU, bool BLEND, bool OUT_BF16>
__global__ __launch_bounds__(256) void gemm_mfma(
    const bf16* __restrict__ Ab, const float* __restrict__ Af,
    const bf16* __restrict__ Wt, const float* __restrict__ bias,
    const bf16* __restrict__ oldx, void* __restrict__ dstv,
    int N, const float* __restrict__ skip_p)
{
  const int wave = threadIdx.x >> 6, lane = threadIdx.x & 63;
  const int lane15 = lane & 15, quad = lane >> 4;
  const long row0 = (long)blockIdx.x * 128 + wave * 32;

  float bv[8];
#pragma unroll
  for (int jc = 0; jc < 8; jc++) bv[jc] = bias[jc * 16 + lane15];

  floatx4 acc[2][8];
#pragma unroll
  for (int i = 0; i < 2; i++)
#pragma unroll
    for (int jc = 0; jc < 8; jc++) acc[i][jc] = (floatx4)(0.f);

#pragma unroll
  for (int kq = 0; kq < 4; kq++) {
    const int k0 = kq * 32 + quad * 8;
    short8 a[2];
#pragma unroll
    for (int i = 0; i < 2; i++) {
      long r = row0 + i * 16 + lane15;
      if (r >= N) r = N - 1;                     // clamped dummy row
      if constexpr (AGELU) {
        const float4 f0 = *(const float4*)(Af + r * CCH + k0);
        const float4 f1 = *(const float4*)(Af + r * CCH + k0 + 4);
        short8 t;
        t[0]=f2bs(gelu_f(f0.x)); t[1]=f2bs(gelu_f(f0.y));
        t[2]=f2bs(gelu_f(f0.z)); t[3]=f2bs(gelu_f(f0.w));
        t[4]=f2bs(gelu_f(f1.x)); t[5]=f2bs(gelu_f(f1.y));
        t[6]=f2bs(gelu_f(f1.z)); t[7]=f2bs(gelu_f(f1.w));
        a[i] = t;
      } else {
        a[i] = *(const short8*)(Ab + r * CCH + k0);
      }
    }
    short8 b[8];
#pragma unroll
    for (int jc = 0; jc < 8; jc++)
      b[jc] = *(const short8*)(Wt + (jc * 16 + lane15) * CCH + k0);
#pragma unroll
    for (int i = 0; i < 2; i++)
#pragma unroll
      for (int jc = 0; jc < 8; jc++)
        acc[i][jc] = __builtin_amdgcn_mfma_f32_16x16x32_bf16(
            a[i], b[jc], acc[i][jc], 0, 0, 0);
  }

  float g = 1.f, gi = 0.f;
  if (BLEND) {
    float sk = *skip_p;
    g = 1.f / (1.f + expf(-sk));
    gi = 1.f - g;
  }
#pragma unroll
  for (int i = 0; i < 2; i++) {
#pragma unroll
    for (int reg = 0; reg < 4; reg++) {
      long r = row0 + i * 16 + quad * 4 + reg;   // C/D: row=quad*4+reg
      if (r < N) {
#pragma unroll
        for (int jc = 0; jc < 8; jc++) {
          float v = acc[i][jc][reg] + bv[jc];
          if (RELU) v = fmaxf(v, 0.f);
          long idx = r * CCH + jc * 16 + lane15; // C/D: col=lane&15
          if (BLEND) v = g * v + gi * b2f(oldx[idx]);
          if (OUT_BF16) ((bf16*)dstv)[idx] = __float2bfloat16(v);
          else          ((float*)dstv)[idx] = v;
        }
      }
    }
  }
}

// ---------------- CSR build --------------------------------------------------
__global__ __launch_bounds__(256) void csr_count(
    const int* __restrict__ dst, int* __restrict__ deg, int* __restrict__ pos)
{
  int e = blockIdx.x * 256 + threadIdx.x;
  if (e < EDGES) pos[e] = atomicAdd(&deg[dst[e]], 1);
}
__global__ __launch_bounds__(256) void csr_alloc(
    const int* __restrict__ deg, int* __restrict__ rowstart,
    int* __restrict__ total, int Ndst)
{
  int n = blockIdx.x * 256 + threadIdx.x;
  if (n < Ndst) rowstart[n] = atomicAdd(total, deg[n]);
}
__global__ __launch_bounds__(256) void csr_fill(
    const int* __restrict__ dst, const int* __restrict__ rowstart,
    const int* __restrict__ pos, int* __restrict__ eidx)
{
  int e = blockIdx.x * 256 + threadIdx.x;
  if (e < EDGES) eidx[rowstart[dst[e]] + pos[e]] = e;
}

// -------- fused per-node attention aggregation (one wave per dst node) ------
template <bool ACCUM>
__global__ __launch_bounds__(256) void agg_rel(
    const int* __restrict__ rowstart, const int* __restrict__ deg,
    const int* __restrict__ eidx, const int* __restrict__ src,
    const bf16* __restrict__ Qb, const bf16* __restrict__ KR,
    const bf16* __restrict__ VR, const float* __restrict__ p_rel,
    float* __restrict__ AGG, int Ndst)
{
  int n = blockIdx.x * 4 + (threadIdx.x >> 6);
  if (n >= Ndst) return;
  int l = threadIdx.x & 63;
  int h = l >> 3;
  float p = p_rel[h] * 0.25f;          // includes 1/sqrt(D)
  union { uint u; bf16 hh[2]; } qv;
  qv.u = *(const uint*)(Qb + (long)n * CCH + 2 * l);
  float qx = b2f(qv.hh[0]), qy = b2f(qv.hh[1]);
  int rs = rowstart[n], g = deg[n];
  float accx = 0.f, accy = 0.f, den = 0.f;
  for (int j = 0; j < g; j++) {
    int e = eidx[rs + j];
    int s = src[e];
    union { uint u; bf16 hh[2]; } kv, vv;
    kv.u = *(const uint*)(KR + (long)s * CCH + 2 * l);
    float prod = qx * b2f(kv.hh[0]) + qy * b2f(kv.hh[1]);
    prod += __shfl_xor(prod, 1);
    prod += __shfl_xor(prod, 2);
    prod += __shfl_xor(prod, 4);       // all 8 lanes of head h hold the dot
    float ev = expf(prod * p);
    den += ev;
    vv.u = *(const uint*)(VR + (long)s * CCH + 2 * l);
    accx += ev * b2f(vv.hh[0]);
    accy += ev * b2f(vv.hh[1]);
  }
  float inv = 1.f / (den + 1e-16f);
  accx *= inv; accy *= inv;
  float* ap = AGG + (long)n * CCH + 2 * l;
  if (ACCUM) {
    float2 old = *(const float2*)ap;
    accx += old.x; accy += old.y;
  }
  *(float2*)ap = make_float2(accx, accy);
}

__global__ __launch_bounds__(256) void zero_out_k(float* __restrict__ out)
{
  long i = ((long)blockIdx.x * 256 + threadIdx.x) * 4;
  *(float4*)(out + i) = make_float4(0.f, 0.f, 0.f, 0.f);
}

extern "C" void kernel_launch(void* const* d_in, const int* in_sizes, int n_in,
                              void* d_out, int out_size, void* d_ws, size_t ws_size,
                              hipStream_t stream)
{
  const int* tok_s = (const int*)d_in[0];
  const int* tok_f = (const int*)d_in[1];
  const int* esrc[3] = {(const int*)d_in[2], (const int*)d_in[4], (const int*)d_in[6]};
  const int* edst[3] = {(const int*)d_in[3], (const int*)d_in[5], (const int*)d_in[7]};
  const float* emb   = (const float*)d_in[8];
  const float* lin_w = (const float*)d_in[9];
  const float* lin_b = (const float*)d_in[10];
  const float* kw = (const float*)d_in[11];
  const float* kb = (const float*)d_in[12];
  const float* qw = (const float*)d_in[13];
  const float* qb = (const float*)d_in[14];
  const float* vw = (const float*)d_in[15];
  const float* vb = (const float*)d_in[16];
  const float* aw = (const float*)d_in[17];
  const float* ab = (const float*)d_in[18];
  const float* skip  = (const float*)d_in[19];
  const float* a_rel = (const float*)d_in[20];
  const float* m_rel = (const float*)d_in[21];
  const float* p_rel = (const float*)d_in[22];

  // ---- ws layout: fp32 | bf16 | int. Total 171,994,256 B. ----
  float* ws   = (float*)d_ws;
  float* AGG  = ws;                    // 19,200,000 f (bf16 alias: pooled E)
  float* KBr  = AGG + 19200000L;       //    128 f
  float* VBr  = KBr + 128;             //    128 f
  bf16*  Xb   = (bf16*)(VBr + 128);    // 19,200,000 bf16 (residual stream)
  bf16*  KRb  = Xb  + 19200000L;       // 12,800,000 bf16 (reused per relation)
  bf16*  VRb  = KRb + 12800000L;       // 12,800,000 bf16
  bf16*  WT   = VRb + 12800000L;       // 10 x 16,384 bf16 (transposed weights)
  bf16*  KWrt = WT  + 163840L;         //     16,384 bf16
  bf16*  VWrt = KWrt + 16384;          //     16,384 bf16
  int*   ip   = (int*)(VWrt + 16384);
  int* deg[3]      = {ip, ip + 100000, ip + 150000};
  int* total       = ip + 250000;                      // 4 counters (3 used)
  int* rowstart[3] = {ip + 250004, ip + 350004, ip + 400004};
  int* eidx[3]     = {ip + 500004, ip + 700004, ip + 900004};
  int* pos         = ip + 1100004;                     // 200,000 (shared)
  bf16* Eb    = (bf16*)AGG;            // pooled embeddings alias (pre-layer)

  bf16*  Qb   = (bf16*)d_out;          // bf16 Q scratch in fp32 d_out,
  float* OUTF = (float*)d_out;         // consumed before epilogue overwrites

  const size_t NEED = (size_t)19200256 * 4 + (size_t)44996608 * 2
                    + (size_t)1300004 * 4;
  if (ws_size < NEED) {            // soft-fail diagnostic: absmax == |ref|max
    zero_out_k<<<19200000 / 4 / 256, 256, 0, stream>>>(OUTF);
    return;
  }

  const int  Ntype[2] = {N_STMT, N_FUNC};
  const long off[2]   = {0L, (long)N_STMT * CCH};
  const int  est[3] = {0, 0, 1}, edt[3] = {0, 1, 0};
  const int  EB = (EDGES + 255) / 256;
  auto nblk = [](int N){ return (N + 127) / 128; };

  // ---- CSR build (per relation), reused by both layers ----
  hipMemsetAsync(ip, 0, (size_t)250004 * 4, stream);
  for (int r = 0; r < 3; r++) {
    int Nd = Ntype[edt[r]];
    csr_count<<<EB, 256, 0, stream>>>(edst[r], deg[r], pos);
    csr_alloc<<<(Nd + 255) / 256, 256, 0, stream>>>(deg[r], rowstart[r], total + r, Nd);
    csr_fill<<<EB, 256, 0, stream>>>(edst[r], rowstart[r], pos, eidx[r]);
  }

  // ---- weight transpose+cast; pooled embeddings ----
  transp_w<<<dim3(64, 10), 256, 0, stream>>>(lin_w, qw, aw, WT);
  pool_embed<<<N_TOT, 128, 0, stream>>>(tok_s, tok_f, emb, Eb);
  // lin: relu(E @ lin_w + lin_b) -> Xb
  for (int t = 0; t < 2; t++)
    gemm_mfma<false, true, false, true><<<nblk(Ntype[t]), 256, 0, stream>>>(
        Eb + off[t], nullptr, WT + t * 16384, lin_b + t * 128, nullptr,
        Xb + off[t], Ntype[t], nullptr);

  for (int l = 0; l < 2; l++) {
    for (int t = 0; t < 2; t++)      // Q -> bf16 scratch in d_out
      gemm_mfma<false, false, false, true><<<nblk(Ntype[t]), 256, 0, stream>>>(
          Xb + off[t], nullptr, WT + (2 + l * 2 + t) * 16384,
          qb + (l * 2 + t) * 128, nullptr, Qb + off[t], Ntype[t], nullptr);

    for (int r = 0; r < 3; r++) {
      int st = est[r], dt = edt[r];
      int Nd = Ntype[dt];
      make_wr<<<64, 256, 0, stream>>>(kw + (l * 2 + st) * 16384, kb + (l * 2 + st) * 128,
                                      a_rel + (l * 3 + r) * 2048, KWrt, KBr);
      make_wr<<<64, 256, 0, stream>>>(vw + (l * 2 + st) * 16384, vb + (l * 2 + st) * 128,
                                      m_rel + (l * 3 + r) * 2048, VWrt, VBr);
      gemm_mfma<false, false, false, true><<<nblk(Ntype[st]), 256, 0, stream>>>(
          Xb + off[st], nullptr, KWrt, KBr, nullptr, KRb, Ntype[st], nullptr);
      gemm_mfma<false, false, false, true><<<nblk(Ntype[st]), 256, 0, stream>>>(
          Xb + off[st], nullptr, VWrt, VBr, nullptr, VRb, Ntype[st], nullptr);
      if (r == 2)   // stmt-dst: accumulate onto r0's aggregate
        agg_rel<true><<<(Nd + 3) / 4, 256, 0, stream>>>(
            rowstart[r], deg[r], eidx[r], esrc[r], Qb + off[dt], KRb, VRb,
            p_rel + (l * 3 + r) * 8, AGG + off[dt], Nd);
      else
        agg_rel<false><<<(Nd + 3) / 4, 256, 0, stream>>>(
            rowstart[r], deg[r], eidx[r], esrc[r], Qb + off[dt], KRb, VRb,
            p_rel + (l * 3 + r) * 8, AGG + off[dt], Nd);
    }
    // out-proj: gelu(AGG) @ aw + ab, blend with Xb. l=0 -> Xb; l=1 -> d_out.
    for (int t = 0; t < 2; t++) {
      if (l == 0)
        gemm_mfma<true, false, true, true><<<nblk(Ntype[t]), 256, 0, stream>>>(
            nullptr, AGG + off[t], WT + (6 + l * 2 + t) * 16384,
            ab + (l * 2 + t) * 128, Xb + off[t], Xb + off[t],
            Ntype[t], skip + l * 2 + t);
      else
        gemm_mfma<true, false, true, false><<<nblk(Ntype[t]), 256, 0, stream>>>(
            nullptr, AGG + off[t], WT + (6 + l * 2 + t) * 16384,
            ab + (l * 2 + t) * 128, Xb + off[t], OUTF + off[t],
            Ntype[t], skip + l * 2 + t);
    }
  }
}

// Round 7
// 1078.994 us; speedup vs baseline: 6.1978x; 1.1306x over previous
//
#include <hip/hip_runtime.h>
#include <hip/hip_bf16.h>

// HGT forward, MI355X. Round 7: traffic diet.
// R6 profile: pool_embed 155us (517MB FETCH, fp32 gather) was #1; rest spread
// over 22 gemms + 6 aggs + 12 make_wr. Changes:
//  - bf16 emb table + wave-per-node pooled gather (16B loads, shfl reduce)
//  - dual-output K/V MFMA gemm (A read once for both)
//  - AGG bf16 (legal since owner-computes, no atomics)
//  - merged stmt agg (r0+r2, one write), CSR stores src directly
//  - all 12 fused relation weights in one dispatch
// ws ~172.3 MB (< proven 214.5), guarded.

typedef __hip_bfloat16 bf16;
typedef __attribute__((ext_vector_type(8))) short short8;
typedef __attribute__((ext_vector_type(4))) float floatx4;

#define N_STMT 100000
#define N_FUNC 50000
#define N_TOT  150000
#define EDGES  200000
#define CCH 128

__device__ __forceinline__ float b2f(bf16 x){ return __bfloat162float(x); }
__device__ __forceinline__ float bs2f(short s){
  union { short s; bf16 h; } u; u.s = s; return __bfloat162float(u.h);
}
__device__ __forceinline__ short f2bs(float x){
  union { bf16 h; short s; } u; u.h = __float2bfloat16(x); return u.s;
}
__device__ __forceinline__ float gelu_f(float x){
  // jax.nn.gelu approximate=True (tanh form)
  return 0.5f * x * (1.f + tanhf(0.7978845608028654f * (x + 0.044715f * x * x * x)));
}

// ---------------- emb fp32 -> bf16 table ------------------------------------
__global__ __launch_bounds__(256) void emb2bf(
    const float* __restrict__ emb, bf16* __restrict__ ebf)
{
  long i = ((long)blockIdx.x * 256 + threadIdx.x) * 8;
  float4 f0 = *(const float4*)(emb + i);
  float4 f1 = *(const float4*)(emb + i + 4);
  short8 o;
  o[0]=f2bs(f0.x); o[1]=f2bs(f0.y); o[2]=f2bs(f0.z); o[3]=f2bs(f0.w);
  o[4]=f2bs(f1.x); o[5]=f2bs(f1.y); o[6]=f2bs(f1.z); o[7]=f2bs(f1.w);
  *(short8*)(ebf + i) = o;
}

// ---------------- pooled embedding: one wave per node -----------------------
// lane: g=lane>>4 token-group, c16=lane&15 -> channels 8*c16..+7 (16B loads)
__global__ __launch_bounds__(256) void pool_embed(
    const int* __restrict__ tok_s, const int* __restrict__ tok_f,
    const bf16* __restrict__ ebf, bf16* __restrict__ E_out)
{
  int n = blockIdx.x * 4 + (threadIdx.x >> 6);
  int lane = threadIdx.x & 63, g = lane >> 4, c16 = lane & 15;
  const int* tok = (n < N_STMT) ? (tok_s + n * 16) : (tok_f + (n - N_STMT) * 16);
  float acc[8] = {0.f,0.f,0.f,0.f,0.f,0.f,0.f,0.f};
#pragma unroll
  for (int j = 0; j < 4; j++) {
    int v = tok[g * 4 + j];
    short8 row = *(const short8*)(ebf + (long)v * CCH + c16 * 8);
#pragma unroll
    for (int q = 0; q < 8; q++) acc[q] += bs2f(row[q]);
  }
#pragma unroll
  for (int q = 0; q < 8; q++) {
    acc[q] += __shfl_xor(acc[q], 16);
    acc[q] += __shfl_xor(acc[q], 32);
  }
  if (g == 0) {
    short8 o;
#pragma unroll
    for (int q = 0; q < 8; q++) o[q] = f2bs(fmaxf(acc[q] * (1.f/16.f), 0.f));
    *(short8*)(E_out + (long)n * CCH + c16 * 8) = o;
  }
}

// ---------------- transpose+cast 10 raw weight matrices ---------------------
__global__ __launch_bounds__(256) void transp_w(
    const float* __restrict__ lin_w, const float* __restrict__ qw,
    const float* __restrict__ aw, bf16* __restrict__ out)
{
  int mat = blockIdx.y;
  const float* src = (mat < 2) ? lin_w + mat * 16384
                   : (mat < 6) ? qw + (mat - 2) * 16384
                               : aw + (mat - 6) * 16384;
  bf16* dst = out + mat * 16384;
  int idx = blockIdx.x * 256 + threadIdx.x;       // n*128+k
  int n = idx >> 7, k = idx & 127;
  dst[idx] = __float2bfloat16(src[k * 128 + n]);
}

// -------- ALL fused relation weights in one dispatch ------------------------
// y=0..5: K mats (z=y), y=6..11: V mats (z=y-6); z=(l*3+r).
// WRT[y][o*128+c] = sum_d W[c][h*16+d]*rel[h][d][e], o=h*16+e (transposed bf16)
__global__ __launch_bounds__(256) void make_wr_all(
    const float* __restrict__ kw, const float* __restrict__ kb,
    const float* __restrict__ vw, const float* __restrict__ vb,
    const float* __restrict__ a_rel, const float* __restrict__ m_rel,
    bf16* __restrict__ WRT, float* __restrict__ Bf)
{
  int y = blockIdx.y;
  bool isV = y >= 6;
  int z = isV ? y - 6 : y;
  int l = z / 3, r = z % 3, st = (r == 2) ? 1 : 0;
  const float* W   = (isV ? vw : kw) + (l * 2 + st) * 16384;
  const float* b   = (isV ? vb : kb) + (l * 2 + st) * 128;
  const float* rel = (isV ? m_rel : a_rel) + z * 2048;
  bf16* Wrt = WRT + y * 16384;
  float* br = Bf + y * 128;

  int idx = blockIdx.x * 256 + threadIdx.x;
  if (idx < 128 * 128) {
    int c = idx >> 7, o = idx & 127;
    int h = o >> 4, e = o & 15;
    float acc = 0.f;
#pragma unroll
    for (int d = 0; d < 16; d++)
      acc += W[c * 128 + h * 16 + d] * rel[h * 256 + d * 16 + e];
    Wrt[o * 128 + c] = __float2bfloat16(acc);
  }
  if (idx < 128) {
    int h = idx >> 4, e = idx & 15;
    float acc = 0.f;
#pragma unroll
    for (int d = 0; d < 16; d++)
      acc += b[h * 16 + d] * rel[h * 256 + d * 16 + e];
    br[idx] = acc;
  }
}

// ---------------- single MFMA GEMM: wave = 32 rows x 128 cols ---------------
template <bool GELU_IN, bool RELU, bool BLEND, bool OUT_BF16>
__global__ __launch_bounds__(256) void gemm_mfma(
    const bf16* __restrict__ Ab, const bf16* __restrict__ Wt,
    const float* __restrict__ bias, const bf16* __restrict__ oldx,
    void* __restrict__ dstv, int N, const float* __restrict__ skip_p)
{
  const int wave = threadIdx.x >> 6, lane = threadIdx.x & 63;
  const int lane15 = lane & 15, quad = lane >> 4;
  const long row0 = (long)blockIdx.x * 128 + wave * 32;

  float bv[8];
#pragma unroll
  for (int jc = 0; jc < 8; jc++) bv[jc] = bias[jc * 16 + lane15];

  floatx4 acc[2][8];
#pragma unroll
  for (int i = 0; i < 2; i++)
#pragma unroll
    for (int jc = 0; jc < 8; jc++) acc[i][jc] = (floatx4)(0.f);

#pragma unroll
  for (int kq = 0; kq < 4; kq++) {
    const int k0 = kq * 32 + quad * 8;
    short8 a[2];
#pragma unroll
    for (int i = 0; i < 2; i++) {
      long r = row0 + i * 16 + lane15;
      if (r >= N) r = N - 1;                     // clamped dummy row
      short8 t = *(const short8*)(Ab + r * CCH + k0);
      if constexpr (GELU_IN) {
#pragma unroll
        for (int q = 0; q < 8; q++) t[q] = f2bs(gelu_f(bs2f(t[q])));
      }
      a[i] = t;
    }
    short8 b[8];
#pragma unroll
    for (int jc = 0; jc < 8; jc++)
      b[jc] = *(const short8*)(Wt + (jc * 16 + lane15) * CCH + k0);
#pragma unroll
    for (int i = 0; i < 2; i++)
#pragma unroll
      for (int jc = 0; jc < 8; jc++)
        acc[i][jc] = __builtin_amdgcn_mfma_f32_16x16x32_bf16(
            a[i], b[jc], acc[i][jc], 0, 0, 0);
  }

  float g = 1.f, gi = 0.f;
  if (BLEND) {
    float sk = *skip_p;
    g = 1.f / (1.f + expf(-sk));
    gi = 1.f - g;
  }
#pragma unroll
  for (int i = 0; i < 2; i++) {
#pragma unroll
    for (int reg = 0; reg < 4; reg++) {
      long r = row0 + i * 16 + quad * 4 + reg;   // C/D: row=quad*4+reg
      if (r < N) {
#pragma unroll
        for (int jc = 0; jc < 8; jc++) {
          float v = acc[i][jc][reg] + bv[jc];
          if (RELU) v = fmaxf(v, 0.f);
          long idx = r * CCH + jc * 16 + lane15; // C/D: col=lane&15
          if (BLEND) v = g * v + gi * b2f(oldx[idx]);
          if (OUT_BF16) ((bf16*)dstv)[idx] = __float2bfloat16(v);
          else          ((float*)dstv)[idx] = v;
        }
      }
    }
  }
}

// ---------------- dual MFMA GEMM: wave = 16 rows, 2 weight mats -------------
// A read once -> out1 = A@W1+b1, out2 = A@W2+b2 (both bf16).
__global__ __launch_bounds__(256) void gemm_kv(
    const bf16* __restrict__ Ab, const bf16* __restrict__ W1t,
    const bf16* __restrict__ W2t, const float* __restrict__ b1,
    const float* __restrict__ b2, bf16* __restrict__ out1,
    bf16* __restrict__ out2, int N)
{
  const int wave = threadIdx.x >> 6, lane = threadIdx.x & 63;
  const int lane15 = lane & 15, quad = lane >> 4;
  const long row0 = (long)blockIdx.x * 64 + wave * 16;

  float bv1[8], bv2[8];
#pragma unroll
  for (int jc = 0; jc < 8; jc++) {
    bv1[jc] = b1[jc * 16 + lane15];
    bv2[jc] = b2[jc * 16 + lane15];
  }
  floatx4 acc[2][8];
#pragma unroll
  for (int i = 0; i < 2; i++)
#pragma unroll
    for (int jc = 0; jc < 8; jc++) acc[i][jc] = (floatx4)(0.f);

#pragma unroll
  for (int kq = 0; kq < 4; kq++) {
    const int k0 = kq * 32 + quad * 8;
    long r = row0 + lane15;
    if (r >= N) r = N - 1;
    short8 a = *(const short8*)(Ab + r * CCH + k0);
#pragma unroll
    for (int jc = 0; jc < 8; jc++) {
      short8 w1 = *(const short8*)(W1t + (jc * 16 + lane15) * CCH + k0);
      short8 w2 = *(const short8*)(W2t + (jc * 16 + lane15) * CCH + k0);
      acc[0][jc] = __builtin_amdgcn_mfma_f32_16x16x32_bf16(a, w1, acc[0][jc], 0, 0, 0);
      acc[1][jc] = __builtin_amdgcn_mfma_f32_16x16x32_bf16(a, w2, acc[1][jc], 0, 0, 0);
    }
  }
#pragma unroll
  for (int reg = 0; reg < 4; reg++) {
    long r = row0 + quad * 4 + reg;
    if (r < N) {
#pragma unroll
      for (int jc = 0; jc < 8; jc++) {
        long idx = r * CCH + jc * 16 + lane15;
        out1[idx] = __float2bfloat16(acc[0][jc][reg] + bv1[jc]);
        out2[idx] = __float2bfloat16(acc[1][jc][reg] + bv2[jc]);
      }
    }
  }
}

// ---------------- CSR build (srcs stored directly) --------------------------
__global__ __launch_bounds__(256) void csr_count(
    const int* __restrict__ dst, int* __restrict__ deg, int* __restrict__ pos)
{
  int e = blockIdx.x * 256 + threadIdx.x;
  if (e < EDGES) pos[e] = atomicAdd(&deg[dst[e]], 1);
}
__global__ __launch_bounds__(256) void csr_alloc(
    const int* __restrict__ deg, int* __restrict__ rowstart,
    int* __restrict__ total, int Ndst)
{
  int n = blockIdx.x * 256 + threadIdx.x;
  if (n < Ndst) rowstart[n] = atomicAdd(total, deg[n]);
}
__global__ __launch_bounds__(256) void csr_fill(
    const int* __restrict__ dst, const int* __restrict__ src,
    const int* __restrict__ rowstart, const int* __restrict__ pos,
    int* __restrict__ srcs)
{
  int e = blockIdx.x * 256 + threadIdx.x;
  if (e < EDGES) srcs[rowstart[dst[e]] + pos[e]] = src[e];
}

// -------- per-relation message for one dst node (device helper) -------------
__device__ __forceinline__ float2 relmsg(
    int rs, int g, const int* __restrict__ srcs,
    const bf16* __restrict__ K, const bf16* __restrict__ V,
    float p, float qx, float qy, int twol)
{
  float ax = 0.f, ay = 0.f, den = 0.f;
  for (int j = 0; j < g; j++) {
    int s = srcs[rs + j];
    union { uint u; bf16 hh[2]; } kv, vv;
    kv.u = *(const uint*)(K + (long)s * CCH + twol);
    float prod = qx * b2f(kv.hh[0]) + qy * b2f(kv.hh[1]);
    prod += __shfl_xor(prod, 1);
    prod += __shfl_xor(prod, 2);
    prod += __shfl_xor(prod, 4);       // 8 lanes of the head share the dot
    float ev = expf(prod * p);
    den += ev;
    vv.u = *(const uint*)(V + (long)s * CCH + twol);
    ax += ev * b2f(vv.hh[0]);
    ay += ev * b2f(vv.hh[1]);
  }
  float inv = 1.f / (den + 1e-16f);
  return make_float2(ax * inv, ay * inv);
}

// -------- stmt-dst aggregation: r0 (stmt src) + r2 (func src), one write ----
__global__ __launch_bounds__(256) void agg_stmt(
    const int* __restrict__ rs0, const int* __restrict__ dg0,
    const int* __restrict__ srcs0, const bf16* __restrict__ K0,
    const bf16* __restrict__ V0, const float* __restrict__ p0,
    const int* __restrict__ rs2, const int* __restrict__ dg2,
    const int* __restrict__ srcs2, const bf16* __restrict__ K2,
    const bf16* __restrict__ V2, const float* __restrict__ p2,
    const bf16* __restrict__ Qb, bf16* __restrict__ AGG)
{
  int n = blockIdx.x * 4 + (threadIdx.x >> 6);
  if (n >= N_STMT) return;
  int l = threadIdx.x & 63, h = l >> 3, twol = 2 * l;
  union { uint u; bf16 hh[2]; } qv;
  qv.u = *(const uint*)(Qb + (long)n * CCH + twol);
  float qx = b2f(qv.hh[0]), qy = b2f(qv.hh[1]);
  float2 m0 = relmsg(rs0[n], dg0[n], srcs0, K0, V0, p0[h] * 0.25f, qx, qy, twol);
  float2 m2 = relmsg(rs2[n], dg2[n], srcs2, K2, V2, p2[h] * 0.25f, qx, qy, twol);
  union { uint u; bf16 hh[2]; } o;
  o.hh[0] = __float2bfloat16(m0.x + m2.x);
  o.hh[1] = __float2bfloat16(m0.y + m2.y);
  *(uint*)(AGG + (long)n * CCH + twol) = o.u;
}

// -------- func-dst aggregation: r1 only -------------------------------------
__global__ __launch_bounds__(256) void agg_func(
    const int* __restrict__ rs1, const int* __restrict__ dg1,
    const int* __restrict__ srcs1, const bf16* __restrict__ K1,
    const bf16* __restrict__ V1, const float* __restrict__ p1,
    const bf16* __restrict__ Qb, bf16* __restrict__ AGG)
{
  int n = blockIdx.x * 4 + (threadIdx.x >> 6);
  if (n >= N_FUNC) return;
  int l = threadIdx.x & 63, h = l >> 3, twol = 2 * l;
  union { uint u; bf16 hh[2]; } qv;
  qv.u = *(const uint*)(Qb + (long)n * CCH + twol);
  float2 m1 = relmsg(rs1[n], dg1[n], srcs1, K1, V1, p1[h] * 0.25f,
                     b2f(qv.hh[0]), b2f(qv.hh[1]), twol);
  union { uint u; bf16 hh[2]; } o;
  o.hh[0] = __float2bfloat16(m1.x);
  o.hh[1] = __float2bfloat16(m1.y);
  *(uint*)(AGG + (long)n * CCH + twol) = o.u;
}

__global__ __launch_bounds__(256) void zero_out_k(float* __restrict__ out)
{
  long i = ((long)blockIdx.x * 256 + threadIdx.x) * 4;
  *(float4*)(out + i) = make_float4(0.f, 0.f, 0.f, 0.f);
}

extern "C" void kernel_launch(void* const* d_in, const int* in_sizes, int n_in,
                              void* d_out, int out_size, void* d_ws, size_t ws_size,
                              hipStream_t stream)
{
  const int* tok_s = (const int*)d_in[0];
  const int* tok_f = (const int*)d_in[1];
  const int* esrc[3] = {(const int*)d_in[2], (const int*)d_in[4], (const int*)d_in[6]};
  const int* edst[3] = {(const int*)d_in[3], (const int*)d_in[5], (const int*)d_in[7]};
  const float* emb   = (const float*)d_in[8];
  const float* lin_w = (const float*)d_in[9];
  const float* lin_b = (const float*)d_in[10];
  const float* kw = (const float*)d_in[11];
  const float* kb = (const float*)d_in[12];
  const float* qw = (const float*)d_in[13];
  const float* qb = (const float*)d_in[14];
  const float* vw = (const float*)d_in[15];
  const float* vb = (const float*)d_in[16];
  const float* aw = (const float*)d_in[17];
  const float* ab = (const float*)d_in[18];
  const float* skip  = (const float*)d_in[19];
  const float* a_rel = (const float*)d_in[20];
  const float* m_rel = (const float*)d_in[21];
  const float* p_rel = (const float*)d_in[22];

  // ---- ws layout. Total 172,327,056 B. ----
  float* Bf   = (float*)d_ws;           // 12 x 128 fused biases (K:0-5, V:6-11)
  bf16*  Xb   = (bf16*)(Bf + 1536);     // 19,200,000  residual stream
  bf16*  AGGb = Xb  + 19200000L;        // 19,200,000  (alias: pooled E)
  bf16*  K0   = AGGb + 19200000L;       // 12,800,000  stmt-src K (r0/r1 reuse)
  bf16*  V0   = K0  + 12800000L;        // 12,800,000
  bf16*  K2   = V0  + 12800000L;        //  6,400,000  func-src K (r2)
  bf16*  V2   = K2  + 6400000L;         //  6,400,000
  bf16*  EBF  = V2  + 6400000L;         //  6,400,000  bf16 emb table
  bf16*  WT   = EBF + 6400000L;         //    163,840  10 transposed raw mats
  bf16*  WRT  = WT  + 163840L;          //    196,608  12 fused rel mats
  int*   ip   = (int*)(WRT + 196608L);
  int* deg[3]      = {ip, ip + 100000, ip + 150000};
  int* total       = ip + 250000;                      // 4 counters (3 used)
  int* rowstart[3] = {ip + 250004, ip + 350004, ip + 400004};
  int* srcs[3]     = {ip + 500004, ip + 700004, ip + 900004};
  int* pos         = ip + 1100004;                     // 200,000 (shared)

  bf16*  Qb   = (bf16*)d_out;          // bf16 Q scratch in fp32 d_out,
  float* OUTF = (float*)d_out;         // consumed before epilogue overwrites

  const size_t NEED = (size_t)1536 * 4 + (size_t)83560448 * 2
                    + (size_t)1300004 * 4;
  if (ws_size < NEED) {            // soft-fail diagnostic: absmax == |ref|max
    zero_out_k<<<19200000 / 4 / 256, 256, 0, stream>>>(OUTF);
    return;
  }

  const int  Ntype[2] = {N_STMT, N_FUNC};
  const long off[2]   = {0L, (long)N_STMT * CCH};
  const int  edt[3] = {0, 1, 0};
  const int  EB = (EDGES + 255) / 256;
  auto nblk1 = [](int N){ return (N + 127) / 128; };  // single gemm
  auto nblk2 = [](int N){ return (N + 63) / 64; };    // dual gemm

  // ---- CSR build (per relation), reused by both layers ----
  hipMemsetAsync(ip, 0, (size_t)250004 * 4, stream);
  for (int r = 0; r < 3; r++) {
    int Nd = Ntype[edt[r]];
    csr_count<<<EB, 256, 0, stream>>>(edst[r], deg[r], pos);
    csr_alloc<<<(Nd + 255) / 256, 256, 0, stream>>>(deg[r], rowstart[r], total + r, Nd);
    csr_fill<<<EB, 256, 0, stream>>>(edst[r], esrc[r], rowstart[r], pos, srcs[r]);
  }

  // ---- one-time prep: bf16 emb, transposed weights, fused rel weights ----
  emb2bf<<<3125, 256, 0, stream>>>(emb, EBF);
  transp_w<<<dim3(64, 10), 256, 0, stream>>>(lin_w, qw, aw, WT);
  make_wr_all<<<dim3(64, 12), 256, 0, stream>>>(kw, kb, vw, vb, a_rel, m_rel, WRT, Bf);

  // ---- prologue: pooled embeddings -> per-type linear+relu -> Xb ----
  pool_embed<<<N_TOT / 4, 256, 0, stream>>>(tok_s, tok_f, EBF, AGGb);
  for (int t = 0; t < 2; t++)
    gemm_mfma<false, true, false, true><<<nblk1(Ntype[t]), 256, 0, stream>>>(
        AGGb + off[t], WT + t * 16384, lin_b + t * 128, nullptr,
        Xb + off[t], Ntype[t], nullptr);

  for (int l = 0; l < 2; l++) {
    for (int t = 0; t < 2; t++)      // Q -> bf16 scratch in d_out
      gemm_mfma<false, false, false, true><<<nblk1(Ntype[t]), 256, 0, stream>>>(
          Xb + off[t], WT + (2 + l * 2 + t) * 16384,
          qb + (l * 2 + t) * 128, nullptr, Qb + off[t], Ntype[t], nullptr);

    int z0 = l * 3 + 0, z1 = l * 3 + 1, z2 = l * 3 + 2;
    // K/V for r0 (stmt src) and r2 (func src)
    gemm_kv<<<nblk2(N_STMT), 256, 0, stream>>>(
        Xb, WRT + z0 * 16384, WRT + (6 + z0) * 16384,
        Bf + z0 * 128, Bf + (6 + z0) * 128, K0, V0, N_STMT);
    gemm_kv<<<nblk2(N_FUNC), 256, 0, stream>>>(
        Xb + off[1], WRT + z2 * 16384, WRT + (6 + z2) * 16384,
        Bf + z2 * 128, Bf + (6 + z2) * 128, K2, V2, N_FUNC);
    agg_stmt<<<(N_STMT + 3) / 4, 256, 0, stream>>>(
        rowstart[0], deg[0], srcs[0], K0, V0, p_rel + z0 * 8,
        rowstart[2], deg[2], srcs[2], K2, V2, p_rel + z2 * 8,
        Qb, AGGb);
    // K/V for r1 (stmt src) -> reuse K0/V0, then func agg
    gemm_kv<<<nblk2(N_STMT), 256, 0, stream>>>(
        Xb, WRT + z1 * 16384, WRT + (6 + z1) * 16384,
        Bf + z1 * 128, Bf + (6 + z1) * 128, K0, V0, N_STMT);
    agg_func<<<(N_FUNC + 3) / 4, 256, 0, stream>>>(
        rowstart[1], deg[1], srcs[1], K0, V0, p_rel + z1 * 8,
        Qb + off[1], AGGb + off[1]);

    // out-proj: gelu(AGGb) @ aw + ab, blend with Xb. l=0 -> Xb; l=1 -> d_out.
    for (int t = 0; t < 2; t++) {
      if (l == 0)
        gemm_mfma<true, false, true, true><<<nblk1(Ntype[t]), 256, 0, stream>>>(
            AGGb + off[t], WT + (6 + l * 2 + t) * 16384,
            ab + (l * 2 + t) * 128, Xb + off[t], Xb + off[t],
            Ntype[t], skip + l * 2 + t);
      else
        gemm_mfma<true, false, true, false><<<nblk1(Ntype[t]), 256, 0, stream>>>(
            AGGb + off[t], WT + (6 + l * 2 + t) * 16384,
            ab + (l * 2 + t) * 128, Xb + off[t], OUTF + off[t],
            Ntype[t], skip + l * 2 + t);
    }
  }
}

// Round 8
// 1069.212 us; speedup vs baseline: 6.2545x; 1.0091x over previous
//
#include <hip/hip_runtime.h>
#include <hip/hip_bf16.h>

// HGT forward, MI355X. Round 8: latency-lean aggregation + fused dispatches.
// R7 profile: agg_stmt 76us latency-bound (VALU 49%, HBM 24%, occ 66%).
//  - KV interleaved per node row: one 8B load/lane/edge (was 2x4B)
//  - srcs batch-prefetched, broadcast via shfl (index load off the chain)
//  - __expf; penta-GEMM (Q,K0,V0,K1,V1 from one X read) + triple for func
//  - one fused agg_all over all 150k nodes; lin/outproj fused across types
//  - EBF aliases KV0 region; ws 210.7 MB (< proven 214.5), guarded.

typedef __hip_bfloat16 bf16;
typedef __attribute__((ext_vector_type(8))) short short8;
typedef __attribute__((ext_vector_type(4))) float floatx4;

#define N_STMT 100000
#define N_FUNC 50000
#define N_TOT  150000
#define EDGES  200000
#define CCH 128
#define NBS1 782   // (N_STMT+127)/128
#define NBF1 391   // (N_FUNC+127)/128

__device__ __forceinline__ float b2f(bf16 x){ return __bfloat162float(x); }
__device__ __forceinline__ float bs2f(short s){
  union { short s; bf16 h; } u; u.s = s; return __bfloat162float(u.h);
}
__device__ __forceinline__ short f2bs(float x){
  union { bf16 h; short s; } u; u.h = __float2bfloat16(x); return u.s;
}
__device__ __forceinline__ float gelu_f(float x){
  return 0.5f * x * (1.f + tanhf(0.7978845608028654f * (x + 0.044715f * x * x * x)));
}

// ---------------- emb fp32 -> bf16 table ------------------------------------
__global__ __launch_bounds__(256) void emb2bf(
    const float* __restrict__ emb, bf16* __restrict__ ebf)
{
  long i = ((long)blockIdx.x * 256 + threadIdx.x) * 8;
  float4 f0 = *(const float4*)(emb + i);
  float4 f1 = *(const float4*)(emb + i + 4);
  short8 o;
  o[0]=f2bs(f0.x); o[1]=f2bs(f0.y); o[2]=f2bs(f0.z); o[3]=f2bs(f0.w);
  o[4]=f2bs(f1.x); o[5]=f2bs(f1.y); o[6]=f2bs(f1.z); o[7]=f2bs(f1.w);
  *(short8*)(ebf + i) = o;
}

// ---------------- pooled embedding: one wave per node -----------------------
__global__ __launch_bounds__(256) void pool_embed(
    const int* __restrict__ tok_s, const int* __restrict__ tok_f,
    const bf16* __restrict__ ebf, bf16* __restrict__ E_out)
{
  int n = blockIdx.x * 4 + (threadIdx.x >> 6);
  int lane = threadIdx.x & 63, g = lane >> 4, c16 = lane & 15;
  const int* tok = (n < N_STMT) ? (tok_s + n * 16) : (tok_f + (n - N_STMT) * 16);
  float acc[8] = {0.f,0.f,0.f,0.f,0.f,0.f,0.f,0.f};
#pragma unroll
  for (int j = 0; j < 4; j++) {
    int v = tok[g * 4 + j];
    short8 row = *(const short8*)(ebf + (long)v * CCH + c16 * 8);
#pragma unroll
    for (int q = 0; q < 8; q++) acc[q] += bs2f(row[q]);
  }
#pragma unroll
  for (int q = 0; q < 8; q++) {
    acc[q] += __shfl_xor(acc[q], 16);
    acc[q] += __shfl_xor(acc[q], 32);
  }
  if (g == 0) {
    short8 o;
#pragma unroll
    for (int q = 0; q < 8; q++) o[q] = f2bs(fmaxf(acc[q] * (1.f/16.f), 0.f));
    *(short8*)(E_out + (long)n * CCH + c16 * 8) = o;
  }
}

// ---------------- transpose+cast 10 raw weight matrices ---------------------
__global__ __launch_bounds__(256) void transp_w(
    const float* __restrict__ lin_w, const float* __restrict__ qw,
    const float* __restrict__ aw, bf16* __restrict__ out)
{
  int mat = blockIdx.y;
  const float* src = (mat < 2) ? lin_w + mat * 16384
                   : (mat < 6) ? qw + (mat - 2) * 16384
                               : aw + (mat - 6) * 16384;
  bf16* dst = out + mat * 16384;
  int idx = blockIdx.x * 256 + threadIdx.x;       // n*128+k
  int n = idx >> 7, k = idx & 127;
  dst[idx] = __float2bfloat16(src[k * 128 + n]);
}

// -------- ALL fused relation weights in one dispatch ------------------------
__global__ __launch_bounds__(256) void make_wr_all(
    const float* __restrict__ kw, const float* __restrict__ kb,
    const float* __restrict__ vw, const float* __restrict__ vb,
    const float* __restrict__ a_rel, const float* __restrict__ m_rel,
    bf16* __restrict__ WRT, float* __restrict__ Bf)
{
  int y = blockIdx.y;
  bool isV = y >= 6;
  int z = isV ? y - 6 : y;
  int l = z / 3, r = z % 3, st = (r == 2) ? 1 : 0;
  const float* W   = (isV ? vw : kw) + (l * 2 + st) * 16384;
  const float* b   = (isV ? vb : kb) + (l * 2 + st) * 128;
  const float* rel = (isV ? m_rel : a_rel) + z * 2048;
  bf16* Wrt = WRT + y * 16384;
  float* br = Bf + y * 128;

  int idx = blockIdx.x * 256 + threadIdx.x;
  if (idx < 128 * 128) {
    int c = idx >> 7, o = idx & 127;
    int h = o >> 4, e = o & 15;
    float acc = 0.f;
#pragma unroll
    for (int d = 0; d < 16; d++)
      acc += W[c * 128 + h * 16 + d] * rel[h * 256 + d * 16 + e];
    Wrt[o * 128 + c] = __float2bfloat16(acc);
  }
  if (idx < 128) {
    int h = idx >> 4, e = idx & 15;
    float acc = 0.f;
#pragma unroll
    for (int d = 0; d < 16; d++)
      acc += b[h * 16 + d] * rel[h * 256 + d * 16 + e];
    br[idx] = acc;
  }
}

// ---------------- fused 2-type MFMA GEMM (lin / out-proj) -------------------
// Grid = NBS1 + NBF1 blocks; block < NBS1 -> stmt rows, else func rows.
template <bool GELU_IN, bool RELU, bool BLEND, bool OUT_BF16>
__global__ __launch_bounds__(256) void gemm_2t(
    const bf16* __restrict__ Ab, const bf16* __restrict__ Wt0,
    const bf16* __restrict__ Wt1, const float* __restrict__ bias0,
    const float* __restrict__ bias1, const bf16* __restrict__ oldx,
    void* __restrict__ dstv, const float* __restrict__ skip2)
{
  const int wave = threadIdx.x >> 6, lane = threadIdx.x & 63;
  const int lane15 = lane & 15, quad = lane >> 4;
  const int bid = blockIdx.x;
  const int type = (bid >= NBS1);
  const long base = type ? (long)N_STMT * CCH : 0;
  const int Nrows = type ? N_FUNC : N_STMT;
  const long row0 = (long)(type ? bid - NBS1 : bid) * 128 + wave * 32;
  const bf16* Wt = type ? Wt1 : Wt0;
  const float* bias = type ? bias1 : bias0;

  float bv[8];
#pragma unroll
  for (int jc = 0; jc < 8; jc++) bv[jc] = bias[jc * 16 + lane15];

  floatx4 acc[2][8];
#pragma unroll
  for (int i = 0; i < 2; i++)
#pragma unroll
    for (int jc = 0; jc < 8; jc++) acc[i][jc] = (floatx4)(0.f);

#pragma unroll
  for (int kq = 0; kq < 4; kq++) {
    const int k0 = kq * 32 + quad * 8;
    short8 a[2];
#pragma unroll
    for (int i = 0; i < 2; i++) {
      long r = row0 + i * 16 + lane15;
      if (r >= Nrows) r = Nrows - 1;
      short8 t = *(const short8*)(Ab + base + r * CCH + k0);
      if constexpr (GELU_IN) {
#pragma unroll
        for (int q = 0; q < 8; q++) t[q] = f2bs(gelu_f(bs2f(t[q])));
      }
      a[i] = t;
    }
    short8 b[8];
#pragma unroll
    for (int jc = 0; jc < 8; jc++)
      b[jc] = *(const short8*)(Wt + (jc * 16 + lane15) * CCH + k0);
#pragma unroll
    for (int i = 0; i < 2; i++)
#pragma unroll
      for (int jc = 0; jc < 8; jc++)
        acc[i][jc] = __builtin_amdgcn_mfma_f32_16x16x32_bf16(
            a[i], b[jc], acc[i][jc], 0, 0, 0);
  }

  float g = 1.f, gi = 0.f;
  if (BLEND) {
    float sk = skip2[type];
    g = 1.f / (1.f + expf(-sk));
    gi = 1.f - g;
  }
#pragma unroll
  for (int i = 0; i < 2; i++) {
#pragma unroll
    for (int reg = 0; reg < 4; reg++) {
      long r = row0 + i * 16 + quad * 4 + reg;
      if (r < Nrows) {
#pragma unroll
        for (int jc = 0; jc < 8; jc++) {
          float v = acc[i][jc][reg] + bv[jc];
          if (RELU) v = fmaxf(v, 0.f);
          long idx = base + r * CCH + jc * 16 + lane15;
          if (BLEND) v = g * v + gi * b2f(oldx[idx]);
          if (OUT_BF16) ((bf16*)dstv)[idx] = __float2bfloat16(v);
          else          ((float*)dstv)[idx] = v;
        }
      }
    }
  }
}

// ---------------- penta GEMM (stmt): Q + KV0 + KV1, X read once -------------
// 16 rows/wave; KV interleaved: K ch c -> row*256 + 4*(c>>1)+(c&1), V at +2.
__global__ __launch_bounds__(256, 2) void gemm_qkv5(
    const bf16* __restrict__ Ab,
    const bf16* __restrict__ WtQ, const float* __restrict__ bQ,
    const bf16* __restrict__ WtK0, const float* __restrict__ bK0,
    const bf16* __restrict__ WtV0, const float* __restrict__ bV0,
    const bf16* __restrict__ WtK1, const float* __restrict__ bK1,
    const bf16* __restrict__ WtV1, const float* __restrict__ bV1,
    bf16* __restrict__ Q, bf16* __restrict__ KV0, bf16* __restrict__ KV1,
    int N)
{
  const int wave = threadIdx.x >> 6, lane = threadIdx.x & 63;
  const int lane15 = lane & 15, quad = lane >> 4;
  const long row0 = (long)blockIdx.x * 64 + wave * 16;

  floatx4 aQ[8], aK0[8], aV0[8], aK1[8], aV1[8];
#pragma unroll
  for (int jc = 0; jc < 8; jc++) {
    aQ[jc] = (floatx4)(0.f); aK0[jc] = (floatx4)(0.f); aV0[jc] = (floatx4)(0.f);
    aK1[jc] = (floatx4)(0.f); aV1[jc] = (floatx4)(0.f);
  }
#pragma unroll
  for (int kq = 0; kq < 4; kq++) {
    const int k0 = kq * 32 + quad * 8;
    long r = row0 + lane15;
    if (r >= N) r = N - 1;
    short8 a = *(const short8*)(Ab + r * CCH + k0);
#pragma unroll
    for (int jc = 0; jc < 8; jc++) {
      const int wrow = (jc * 16 + lane15) * CCH + k0;
      aQ[jc]  = __builtin_amdgcn_mfma_f32_16x16x32_bf16(a, *(const short8*)(WtQ  + wrow), aQ[jc], 0, 0, 0);
      aK0[jc] = __builtin_amdgcn_mfma_f32_16x16x32_bf16(a, *(const short8*)(WtK0 + wrow), aK0[jc], 0, 0, 0);
      aV0[jc] = __builtin_amdgcn_mfma_f32_16x16x32_bf16(a, *(const short8*)(WtV0 + wrow), aV0[jc], 0, 0, 0);
      aK1[jc] = __builtin_amdgcn_mfma_f32_16x16x32_bf16(a, *(const short8*)(WtK1 + wrow), aK1[jc], 0, 0, 0);
      aV1[jc] = __builtin_amdgcn_mfma_f32_16x16x32_bf16(a, *(const short8*)(WtV1 + wrow), aV1[jc], 0, 0, 0);
    }
  }
  float bQv[8], bK0v[8], bV0v[8], bK1v[8], bV1v[8];
#pragma unroll
  for (int jc = 0; jc < 8; jc++) {
    int c = jc * 16 + lane15;
    bQv[jc] = bQ[c]; bK0v[jc] = bK0[c]; bV0v[jc] = bV0[c];
    bK1v[jc] = bK1[c]; bV1v[jc] = bV1[c];
  }
#pragma unroll
  for (int reg = 0; reg < 4; reg++) {
    long r = row0 + quad * 4 + reg;
    if (r < N) {
#pragma unroll
      for (int jc = 0; jc < 8; jc++) {
        int c = jc * 16 + lane15;
        int ik = 4 * (c >> 1) + (c & 1);
        Q[r * CCH + c]        = __float2bfloat16(aQ[jc][reg] + bQv[jc]);
        KV0[r * 256 + ik]     = __float2bfloat16(aK0[jc][reg] + bK0v[jc]);
        KV0[r * 256 + ik + 2] = __float2bfloat16(aV0[jc][reg] + bV0v[jc]);
        KV1[r * 256 + ik]     = __float2bfloat16(aK1[jc][reg] + bK1v[jc]);
        KV1[r * 256 + ik + 2] = __float2bfloat16(aV1[jc][reg] + bV1v[jc]);
      }
    }
  }
}

// ---------------- triple GEMM (func): Q + KV2 -------------------------------
__global__ __launch_bounds__(256) void gemm_qkv3(
    const bf16* __restrict__ Ab,
    const bf16* __restrict__ WtQ, const float* __restrict__ bQ,
    const bf16* __restrict__ WtK, const float* __restrict__ bK,
    const bf16* __restrict__ WtV, const float* __restrict__ bV,
    bf16* __restrict__ Q, bf16* __restrict__ KV, int N)
{
  const int wave = threadIdx.x >> 6, lane = threadIdx.x & 63;
  const int lane15 = lane & 15, quad = lane >> 4;
  const long row0 = (long)blockIdx.x * 64 + wave * 16;

  floatx4 aQ[8], aK[8], aV[8];
#pragma unroll
  for (int jc = 0; jc < 8; jc++) {
    aQ[jc] = (floatx4)(0.f); aK[jc] = (floatx4)(0.f); aV[jc] = (floatx4)(0.f);
  }
#pragma unroll
  for (int kq = 0; kq < 4; kq++) {
    const int k0 = kq * 32 + quad * 8;
    long r = row0 + lane15;
    if (r >= N) r = N - 1;
    short8 a = *(const short8*)(Ab + r * CCH + k0);
#pragma unroll
    for (int jc = 0; jc < 8; jc++) {
      const int wrow = (jc * 16 + lane15) * CCH + k0;
      aQ[jc] = __builtin_amdgcn_mfma_f32_16x16x32_bf16(a, *(const short8*)(WtQ + wrow), aQ[jc], 0, 0, 0);
      aK[jc] = __builtin_amdgcn_mfma_f32_16x16x32_bf16(a, *(const short8*)(WtK + wrow), aK[jc], 0, 0, 0);
      aV[jc] = __builtin_amdgcn_mfma_f32_16x16x32_bf16(a, *(const short8*)(WtV + wrow), aV[jc], 0, 0, 0);
    }
  }
  float bQv[8], bKv[8], bVv[8];
#pragma unroll
  for (int jc = 0; jc < 8; jc++) {
    int c = jc * 16 + lane15;
    bQv[jc] = bQ[c]; bKv[jc] = bK[c]; bVv[jc] = bV[c];
  }
#pragma unroll
  for (int reg = 0; reg < 4; reg++) {
    long r = row0 + quad * 4 + reg;
    if (r < N) {
#pragma unroll
      for (int jc = 0; jc < 8; jc++) {
        int c = jc * 16 + lane15;
        int ik = 4 * (c >> 1) + (c & 1);
        Q[r * CCH + c]       = __float2bfloat16(aQ[jc][reg] + bQv[jc]);
        KV[r * 256 + ik]     = __float2bfloat16(aK[jc][reg] + bKv[jc]);
        KV[r * 256 + ik + 2] = __float2bfloat16(aV[jc][reg] + bVv[jc]);
      }
    }
  }
}

// ---------------- CSR build (srcs stored directly) --------------------------
__global__ __launch_bounds__(256) void csr_count(
    const int* __restrict__ dst, int* __restrict__ deg, int* __restrict__ pos)
{
  int e = blockIdx.x * 256 + threadIdx.x;
  if (e < EDGES) pos[e] = atomicAdd(&deg[dst[e]], 1);
}
__global__ __launch_bounds__(256) void csr_alloc(
    const int* __restrict__ deg, int* __restrict__ rowstart,
    int* __restrict__ total, int Ndst)
{
  int n = blockIdx.x * 256 + threadIdx.x;
  if (n < Ndst) rowstart[n] = atomicAdd(total, deg[n]);
}
__global__ __launch_bounds__(256) void csr_fill(
    const int* __restrict__ dst, const int* __restrict__ src,
    const int* __restrict__ rowstart, const int* __restrict__ pos,
    int* __restrict__ srcs)
{
  int e = blockIdx.x * 256 + threadIdx.x;
  if (e < EDGES) srcs[rowstart[dst[e]] + pos[e]] = src[e];
}

// -------- per-relation message (device helper, interleaved KV) --------------
__device__ __forceinline__ float2 relmsg(
    int rs, int g, const int* __restrict__ srcs,
    const bf16* __restrict__ KV, float p, float qx, float qy, int l)
{
  float ax = 0.f, ay = 0.f, den = 0.f;
  for (int j0 = 0; j0 < g; j0 += 64) {
    int cnt = g - j0; if (cnt > 64) cnt = 64;
    int sl = srcs[rs + j0 + (l < cnt ? l : cnt - 1)];
    for (int j = 0; j < cnt; j++) {
      int s = __shfl(sl, j);
      union { uint2 u; bf16 hh[4]; } kv;
      kv.u = *(const uint2*)(KV + (long)s * 256 + 4 * l);
      float prod = qx * b2f(kv.hh[0]) + qy * b2f(kv.hh[1]);
      prod += __shfl_xor(prod, 1);
      prod += __shfl_xor(prod, 2);
      prod += __shfl_xor(prod, 4);
      float ev = __expf(prod * p);
      den += ev;
      ax += ev * b2f(kv.hh[2]);
      ay += ev * b2f(kv.hh[3]);
    }
  }
  float inv = 1.f / (den + 1e-16f);
  return make_float2(ax * inv, ay * inv);
}

// -------- fused aggregation over ALL nodes (one wave per dst node) ----------
__global__ __launch_bounds__(256) void agg_all(
    const int* __restrict__ rs0, const int* __restrict__ dg0, const int* __restrict__ srcs0,
    const int* __restrict__ rs1, const int* __restrict__ dg1, const int* __restrict__ srcs1,
    const int* __restrict__ rs2, const int* __restrict__ dg2, const int* __restrict__ srcs2,
    const bf16* __restrict__ KV0, const bf16* __restrict__ KV1,
    const bf16* __restrict__ KV2, const float* __restrict__ pl,
    const bf16* __restrict__ Qb, bf16* __restrict__ AGGb)
{
  int n = blockIdx.x * 4 + (threadIdx.x >> 6);
  if (n >= N_TOT) return;
  int l = threadIdx.x & 63, h = l >> 3;
  union { uint u; bf16 hh[2]; } qv;
  qv.u = *(const uint*)(Qb + (long)n * CCH + 2 * l);
  float qx = b2f(qv.hh[0]), qy = b2f(qv.hh[1]);
  float rx, ry;
  if (n < N_STMT) {
    float2 m0 = relmsg(rs0[n], dg0[n], srcs0, KV0, pl[h] * 0.25f, qx, qy, l);
    float2 m2 = relmsg(rs2[n], dg2[n], srcs2, KV2, pl[16 + h] * 0.25f, qx, qy, l);
    rx = m0.x + m2.x; ry = m0.y + m2.y;
  } else {
    int nf = n - N_STMT;
    float2 m1 = relmsg(rs1[nf], dg1[nf], srcs1, KV1, pl[8 + h] * 0.25f, qx, qy, l);
    rx = m1.x; ry = m1.y;
  }
  union { uint u; bf16 hh[2]; } o;
  o.hh[0] = __float2bfloat16(rx);
  o.hh[1] = __float2bfloat16(ry);
  *(uint*)(AGGb + (long)n * CCH + 2 * l) = o.u;
}

__global__ __launch_bounds__(256) void zero_out_k(float* __restrict__ out)
{
  long i = ((long)blockIdx.x * 256 + threadIdx.x) * 4;
  *(float4*)(out + i) = make_float4(0.f, 0.f, 0.f, 0.f);
}

extern "C" void kernel_launch(void* const* d_in, const int* in_sizes, int n_in,
                              void* d_out, int out_size, void* d_ws, size_t ws_size,
                              hipStream_t stream)
{
  const int* tok_s = (const int*)d_in[0];
  const int* tok_f = (const int*)d_in[1];
  const int* esrc[3] = {(const int*)d_in[2], (const int*)d_in[4], (const int*)d_in[6]};
  const int* edst[3] = {(const int*)d_in[3], (const int*)d_in[5], (const int*)d_in[7]};
  const float* emb   = (const float*)d_in[8];
  const float* lin_w = (const float*)d_in[9];
  const float* lin_b = (const float*)d_in[10];
  const float* kw = (const float*)d_in[11];
  const float* kb = (const float*)d_in[12];
  const float* qw = (const float*)d_in[13];
  const float* qb = (const float*)d_in[14];
  const float* vw = (const float*)d_in[15];
  const float* vb = (const float*)d_in[16];
  const float* aw = (const float*)d_in[17];
  const float* ab = (const float*)d_in[18];
  const float* skip  = (const float*)d_in[19];
  const float* a_rel = (const float*)d_in[20];
  const float* m_rel = (const float*)d_in[21];
  const float* p_rel = (const float*)d_in[22];

  // ---- ws layout. Total 210,727,056 B. ----
  float* Bf   = (float*)d_ws;           // 12 x 128 fused biases
  bf16*  Xb   = (bf16*)(Bf + 1536);     // 19,200,000  residual stream
  bf16*  AGGb = Xb  + 19200000L;        // 19,200,000  (alias: pooled E)
  bf16*  KV0  = AGGb + 19200000L;       // 25,600,000  stmt r0 KV interleaved
  bf16*  KV1  = KV0 + 25600000L;        // 25,600,000  stmt r1 KV
  bf16*  KV2  = KV1 + 25600000L;        // 12,800,000  func r2 KV
  bf16*  WT   = KV2 + 12800000L;        //    163,840  10 transposed raw mats
  bf16*  WRT  = WT  + 163840L;          //    196,608  12 fused rel mats
  int*   ip   = (int*)(WRT + 196608L);
  int* deg[3]      = {ip, ip + 100000, ip + 150000};
  int* total       = ip + 250000;                      // 4 counters (3 used)
  int* rowstart[3] = {ip + 250004, ip + 350004, ip + 400004};
  int* srcs[3]     = {ip + 500004, ip + 700004, ip + 900004};
  int* pos         = ip + 1100004;                     // 200,000 (shared)
  bf16* EBF   = KV0;                    // 6,400,000 alias: bf16 emb table,
                                        // dead before KV0 is first written
  bf16*  Qb   = (bf16*)d_out;          // bf16 Q scratch in fp32 d_out,
  float* OUTF = (float*)d_out;         // consumed before epilogue overwrites

  const size_t NEED = (size_t)1536 * 4 + (size_t)102760448 * 2
                    + (size_t)1300004 * 4;
  if (ws_size < NEED) {            // soft-fail diagnostic: absmax == |ref|max
    zero_out_k<<<19200000 / 4 / 256, 256, 0, stream>>>(OUTF);
    return;
  }

  const int  Ntype[2] = {N_STMT, N_FUNC};
  const int  edt[3] = {0, 1, 0};
  const int  EB = (EDGES + 255) / 256;

  // ---- CSR build (per relation), reused by both layers ----
  hipMemsetAsync(ip, 0, (size_t)250004 * 4, stream);
  for (int r = 0; r < 3; r++) {
    int Nd = Ntype[edt[r]];
    csr_count<<<EB, 256, 0, stream>>>(edst[r], deg[r], pos);
    csr_alloc<<<(Nd + 255) / 256, 256, 0, stream>>>(deg[r], rowstart[r], total + r, Nd);
    csr_fill<<<EB, 256, 0, stream>>>(edst[r], esrc[r], rowstart[r], pos, srcs[r]);
  }

  // ---- one-time prep ----
  emb2bf<<<3125, 256, 0, stream>>>(emb, EBF);
  transp_w<<<dim3(64, 10), 256, 0, stream>>>(lin_w, qw, aw, WT);
  make_wr_all<<<dim3(64, 12), 256, 0, stream>>>(kw, kb, vw, vb, a_rel, m_rel, WRT, Bf);

  // ---- prologue: pooled embeddings -> fused per-type linear+relu -> Xb ----
  pool_embed<<<N_TOT / 4, 256, 0, stream>>>(tok_s, tok_f, EBF, AGGb);
  gemm_2t<false, true, false, true><<<NBS1 + NBF1, 256, 0, stream>>>(
      AGGb, WT, WT + 16384, lin_b, lin_b + 128, nullptr, Xb, nullptr);

  for (int l = 0; l < 2; l++) {
    int z0 = l * 3 + 0, z1 = l * 3 + 1, z2 = l * 3 + 2;
    // stmt: Q + KV(r0) + KV(r1), X read once
    gemm_qkv5<<<(N_STMT + 63) / 64, 256, 0, stream>>>(
        Xb,
        WT + (2 + l * 2) * 16384, qb + (l * 2) * 128,
        WRT + z0 * 16384, Bf + z0 * 128, WRT + (6 + z0) * 16384, Bf + (6 + z0) * 128,
        WRT + z1 * 16384, Bf + z1 * 128, WRT + (6 + z1) * 16384, Bf + (6 + z1) * 128,
        Qb, KV0, KV1, N_STMT);
    // func: Q + KV(r2)
    gemm_qkv3<<<(N_FUNC + 63) / 64, 256, 0, stream>>>(
        Xb + (long)N_STMT * CCH,
        WT + (2 + l * 2 + 1) * 16384, qb + (l * 2 + 1) * 128,
        WRT + z2 * 16384, Bf + z2 * 128, WRT + (6 + z2) * 16384, Bf + (6 + z2) * 128,
        Qb + (long)N_STMT * CCH, KV2, N_FUNC);
    // fused aggregation over all nodes
    agg_all<<<(N_TOT + 3) / 4, 256, 0, stream>>>(
        rowstart[0], deg[0], srcs[0], rowstart[1], deg[1], srcs[1],
        rowstart[2], deg[2], srcs[2], KV0, KV1, KV2,
        p_rel + l * 24, Qb, AGGb);
    // fused out-proj + gated skip blend. l=0 -> Xb; l=1 -> fp32 d_out.
    if (l == 0)
      gemm_2t<true, false, true, true><<<NBS1 + NBF1, 256, 0, stream>>>(
          AGGb, WT + 6 * 16384, WT + 7 * 16384, ab, ab + 128,
          Xb, Xb, skip);
    else
      gemm_2t<true, false, true, false><<<NBS1 + NBF1, 256, 0, stream>>>(
          AGGb, WT + 8 * 16384, WT + 9 * 16384, ab + 256, ab + 384,
          Xb, OUTF, skip + 2);
  }
}